// Round 4
// baseline (287.328 us; speedup 1.0000x reference)
//
#include <hip/hip_runtime.h>
#include <hip/hip_bf16.h>

// Problem constants
#define BB 8
#define SS 1024
#define HH 512
#define DD 64

typedef unsigned short u16;
typedef short v8s __attribute__((ext_vector_type(8)));   // 8 x bf16 (bit pattern)
typedef float v4f __attribute__((ext_vector_type(4)));

__device__ __forceinline__ float bf2f(u16 u) {
    union { unsigned int i; float f; } v; v.i = ((unsigned int)u) << 16; return v.f;
}
__device__ __forceinline__ u16 f2bf(float f) {
    union { float f; unsigned int i; } v; v.f = f;
    unsigned int u = v.i;
    unsigned int r = u + 0x7fffu + ((u >> 16) & 1u);   // RNE
    return (u16)(r >> 16);
}

// async 16B global->LDS DMA: lane L's data lands at ldsbase + L*16
__device__ __forceinline__ void gload16(const u16* g, u16* l) {
    __builtin_amdgcn_global_load_lds(
        (const __attribute__((address_space(1))) void*)g,
        (__attribute__((address_space(3))) void*)l,
        16, 0, 0);
}

// ---------------------------------------------------------------------------
// Shared GEMM geometry (BK=64): LDS rows of 64 bf16 = 8 chunks of 16B.
// Physical chunk p of row r holds logical chunk p ^ (r&7) (conflict-free b128).
// Staging: thread t=64w+lane, instr i: row = i*32 + w*8 + (lane>>3),
//          phys chunk = lane&7, global col chunk = (lane&7) ^ (lane>>3).
//
// tile_1024: 128x128 tile x K=1024 NT product, bf16 out. mirror!=0 (symmetric
// product, off-diagonal tile): ALSO writes C[tn..][tm..] = tile^T directly
// from registers — C-layout gives each lane 4 consecutive rows of one column,
// i.e. 4 consecutive u16 of the transposed tile -> one packed 8B store.
// ---------------------------------------------------------------------------
__device__ __forceinline__ void tile_1024(
    const u16* __restrict__ Xb, const u16* __restrict__ Yb,
    u16* __restrict__ Cd, int tm, int tn, u16* Xs, u16* Ys, int mirror)
{
    int t = threadIdx.x, lane = t & 63, w = t >> 6;
    int wm = (w & 1) << 6, wn = (w >> 1) << 6;
    int fr = lane & 15, q = lane >> 4, m7 = fr & 7;
    int subrow = lane >> 3, cch = (lane & 7) ^ subrow;

    const u16* xg[4]; const u16* yg[4]; u16* xl[4]; u16* yl[4];
    #pragma unroll
    for (int i = 0; i < 4; i++) {
        int r = i * 32 + w * 8 + subrow;
        xg[i] = Xb + (long)(tm + r) * 1024 + cch * 8;
        yg[i] = Yb + (long)(tn + r) * 1024 + cch * 8;
        xl[i] = Xs + (i * 32 + w * 8) * 64;
        yl[i] = Ys + (i * 32 + w * 8) * 64;
    }

    v4f acc[4][4];
    #pragma unroll
    for (int i = 0; i < 4; i++)
        #pragma unroll
        for (int j = 0; j < 4; j++) {
            acc[i][j][0] = 0.f; acc[i][j][1] = 0.f; acc[i][j][2] = 0.f; acc[i][j][3] = 0.f;
        }

    for (int k0 = 0; k0 < 1024; k0 += 64) {
        __syncthreads();
        #pragma unroll
        for (int i = 0; i < 4; i++) { gload16(xg[i] + k0, xl[i]); gload16(yg[i] + k0, yl[i]); }
        __syncthreads();
        v8s af[2][4], bfr[2][4];
        #pragma unroll
        for (int h = 0; h < 2; h++) {
            int ca = (((h << 2) + q) ^ m7) << 3;
            #pragma unroll
            for (int s = 0; s < 4; s++) {
                af[h][s]  = *(const v8s*)(Xs + (wm + s * 16 + fr) * 64 + ca);
                bfr[h][s] = *(const v8s*)(Ys + (wn + s * 16 + fr) * 64 + ca);
            }
        }
        #pragma unroll
        for (int h = 0; h < 2; h++)
            #pragma unroll
            for (int i = 0; i < 4; i++)
                #pragma unroll
                for (int j = 0; j < 4; j++)
                    acc[i][j] = __builtin_amdgcn_mfma_f32_16x16x32_bf16(af[h][i], bfr[h][j], acc[i][j], 0, 0, 0);
    }
    #pragma unroll
    for (int i = 0; i < 4; i++) {
        int rowb = tm + wm + i * 16 + q * 4;
        #pragma unroll
        for (int j = 0; j < 4; j++) {
            int col = tn + wn + j * 16 + fr;
            ushort4 pv;
            pv.x = f2bf(acc[i][j][0]); pv.y = f2bf(acc[i][j][1]);
            pv.z = f2bf(acc[i][j][2]); pv.w = f2bf(acc[i][j][3]);
            #pragma unroll
            for (int r = 0; r < 4; r++)
                Cd[(long)(rowb + r) * 1024 + col] = ((u16*)&pv)[r];
            if (mirror)   // transposed tile: 4 consecutive u16 at row=col
                *(ushort4*)(Cd + (long)col * 1024 + rowb) = pv;
        }
    }
}

// ---------------------------------------------------------------------------
// hopV projection tile (K=64, 128 rows of V x 128 rows of hopWb), writing the
// TRANSPOSED result directly to hopVT[(hop*8+z)][e][s]: each lane's acc[i][j]
// holds 4 consecutive s-rows of one e-column -> one packed 8B store.
// ---------------------------------------------------------------------------
__device__ __forceinline__ void hopv_tile(
    const u16* __restrict__ Vrows, const u16* __restrict__ Hw,
    u16* __restrict__ hopVT, int tm, u16* Xs, u16* Ys)
{
    int t = threadIdx.x, lane = t & 63, w = t >> 6;
    int wm = (w & 1) << 6, wn = (w >> 1) << 6;
    int fr = lane & 15, q = lane >> 4, m7 = fr & 7;
    int subrow = lane >> 3, cch = (lane & 7) ^ subrow;

    #pragma unroll
    for (int i = 0; i < 4; i++) {
        int r = i * 32 + w * 8 + subrow;
        gload16(Vrows + (long)(tm + r) * 64 + cch * 8, Xs + (i * 32 + w * 8) * 64);
        gload16(Hw + (long)r * 64 + cch * 8, Ys + (i * 32 + w * 8) * 64);
    }
    __syncthreads();

    v4f acc[4][4];
    #pragma unroll
    for (int i = 0; i < 4; i++)
        #pragma unroll
        for (int j = 0; j < 4; j++) {
            acc[i][j][0] = 0.f; acc[i][j][1] = 0.f; acc[i][j][2] = 0.f; acc[i][j][3] = 0.f;
        }
    v8s af[2][4], bfr[2][4];
    #pragma unroll
    for (int h = 0; h < 2; h++) {
        int ca = (((h << 2) + q) ^ m7) << 3;
        #pragma unroll
        for (int s = 0; s < 4; s++) {
            af[h][s]  = *(const v8s*)(Xs + (wm + s * 16 + fr) * 64 + ca);
            bfr[h][s] = *(const v8s*)(Ys + (wn + s * 16 + fr) * 64 + ca);
        }
    }
    #pragma unroll
    for (int h = 0; h < 2; h++)
        #pragma unroll
        for (int i = 0; i < 4; i++)
            #pragma unroll
            for (int j = 0; j < 4; j++)
                acc[i][j] = __builtin_amdgcn_mfma_f32_16x16x32_bf16(af[h][i], bfr[h][j], acc[i][j], 0, 0, 0);

    int z = tm >> 10, sb = tm & 1023;
    #pragma unroll
    for (int i = 0; i < 4; i++) {
        int rowb = wm + i * 16 + q * 4;
        #pragma unroll
        for (int j = 0; j < 4; j++) {
            int colY = wn + j * 16 + fr;
            int hop = colY >> 6, e = colY & 63;
            ushort4 pv;
            pv.x = f2bf(acc[i][j][0]); pv.y = f2bf(acc[i][j][1]);
            pv.z = f2bf(acc[i][j][2]); pv.w = f2bf(acc[i][j][3]);
            *(ushort4*)(hopVT + (long)(hop * 8 + z) * 65536 + (long)e * 1024 + sb + rowb) = pv;
        }
    }
}

// 128x64 F@H^T tile over K-range [y*256,(y+1)*256). Fs:128x64, Hs:64x64 LDS.
__device__ __forceinline__ void hop_tile(
    const u16* __restrict__ Fb, const u16* __restrict__ Hb,
    int y, int tmt, float* __restrict__ Pd, u16* Fs, u16* Hs)
{
    int tm = tmt * 128, kb = y * 256;
    int t = threadIdx.x, lane = t & 63, w = t >> 6;
    int fr = lane & 15, q = lane >> 4, m7 = fr & 7;
    int subrow = lane >> 3, cch = (lane & 7) ^ subrow;

    const u16* fg[4]; u16* fl[4]; const u16* hg[2]; u16* hl[2];
    #pragma unroll
    for (int i = 0; i < 4; i++) {
        int r = i * 32 + w * 8 + subrow;
        fg[i] = Fb + (long)(tm + r) * 1024 + cch * 8;
        fl[i] = Fs + (i * 32 + w * 8) * 64;
    }
    #pragma unroll
    for (int i = 0; i < 2; i++) {
        int r = i * 32 + w * 8 + subrow;
        hg[i] = Hb + (long)r * 1024 + cch * 8;
        hl[i] = Hs + (i * 32 + w * 8) * 64;
    }

    v4f acc[2][4];
    #pragma unroll
    for (int i = 0; i < 2; i++)
        #pragma unroll
        for (int j = 0; j < 4; j++) {
            acc[i][j][0] = 0.f; acc[i][j][1] = 0.f; acc[i][j][2] = 0.f; acc[i][j][3] = 0.f;
        }

    for (int k0 = kb; k0 < kb + 256; k0 += 64) {
        __syncthreads();
        #pragma unroll
        for (int i = 0; i < 4; i++) gload16(fg[i] + k0, fl[i]);
        #pragma unroll
        for (int i = 0; i < 2; i++) gload16(hg[i] + k0, hl[i]);
        __syncthreads();
        v8s af[2][2], bfr[2][4];
        #pragma unroll
        for (int h = 0; h < 2; h++) {
            int ca = (((h << 2) + q) ^ m7) << 3;
            #pragma unroll
            for (int s = 0; s < 2; s++)
                af[h][s] = *(const v8s*)(Fs + (w * 32 + s * 16 + fr) * 64 + ca);
            #pragma unroll
            for (int s = 0; s < 4; s++)
                bfr[h][s] = *(const v8s*)(Hs + (s * 16 + fr) * 64 + ca);
        }
        #pragma unroll
        for (int h = 0; h < 2; h++)
            #pragma unroll
            for (int i = 0; i < 2; i++)
                #pragma unroll
                for (int j = 0; j < 4; j++)
                    acc[i][j] = __builtin_amdgcn_mfma_f32_16x16x32_bf16(af[h][i], bfr[h][j], acc[i][j], 0, 0, 0);
    }
    #pragma unroll
    for (int i = 0; i < 2; i++) {
        int rowb = tm + w * 32 + i * 16 + q * 4;
        #pragma unroll
        for (int j = 0; j < 4; j++) {
            int col = j * 16 + fr;
            #pragma unroll
            for (int r = 0; r < 4; r++)
                Pd[(long)(rowb + r) * 64 + col] = acc[i][j][r];
        }
    }
}

// fused prob_log/sigmoid/row-norm for one row (wave-collective, 64 lanes).
__device__ __forceinline__ void fused_row(
    const u16* __restrict__ r1, const u16* __restrict__ r2, const u16* __restrict__ r3,
    float w0, float w1, float w2, float b0, u16* __restrict__ Frow, int lane)
{
    int base = lane << 4;
    union U { uint4 v; u16 s[8]; };
    U a[2], b[2], c[2];
    a[0].v = *(const uint4*)(r1 + base); a[1].v = *(const uint4*)(r1 + base + 8);
    b[0].v = *(const uint4*)(r2 + base); b[1].v = *(const uint4*)(r2 + base + 8);
    c[0].v = *(const uint4*)(r3 + base); c[1].v = *(const uint4*)(r3 + base + 8);
    float m1[16], m2[16], m3[16];
    float s1 = 0.f, s2 = 0.f, s3 = 0.f;
    #pragma unroll
    for (int h = 0; h < 2; h++)
        #pragma unroll
        for (int e = 0; e < 8; e++) {
            int k = h * 8 + e;
            m1[k] = bf2f(a[h].s[e]); m2[k] = bf2f(b[h].s[e]); m3[k] = bf2f(c[h].s[e]);
            s1 += m1[k]; s2 += m2[k]; s3 += m3[k];
        }
    #pragma unroll
    for (int o = 1; o < 64; o <<= 1) {
        s1 += __shfl_xor(s1, o); s2 += __shfl_xor(s2, o); s3 += __shfl_xor(s3, o);
    }
    float i1 = 1.f / (s1 + 1e-6f), i2 = 1.f / (s2 + 1e-6f), i3 = 1.f / (s3 + 1e-6f);
    float sig[16];
    float ssum = 0.f;
    #pragma unroll
    for (int k = 0; k < 16; k++) {
        float p1 = fminf(fmaxf(m1[k] * i1, 1e-6f), 1.0f - 1e-6f);
        float p2 = fminf(fmaxf(m2[k] * i2, 1e-6f), 1.0f - 1e-6f);
        float p3 = fminf(fmaxf(m3[k] * i3, 1e-6f), 1.0f - 1e-6f);
        float l1 = __logf(p1 / (1.0f - p1 + 1e-6f));
        float l2 = __logf(p2 / (1.0f - p2 + 1e-6f));
        float l3 = __logf(p3 / (1.0f - p3 + 1e-6f));
        float lg = b0 + w0 * l1 + w1 * l2 + w2 * l3;
        float sg = 1.0f / (1.0f + __expf(-lg));
        sig[k] = sg; ssum += sg;
    }
    #pragma unroll
    for (int o = 1; o < 64; o <<= 1) ssum += __shfl_xor(ssum, o);
    float inv = 1.0f / (ssum + 1e-6f);
    U o0, o1;
    #pragma unroll
    for (int e = 0; e < 8; e++) { o0.s[e] = f2bf(sig[e] * inv); o1.s[e] = f2bf(sig[8 + e] * inv); }
    *(uint4*)(Frow + base) = o0.v;
    *(uint4*)(Frow + base + 8) = o1.v;
}

// ---------------------------------------------------------------------------
// Fused QK^T + bias + temperature + softmax -> A and AT (no-max softmax; see
// R3 notes) — blocks 0..511. Blocks 512..575: hopV projection rider -> hopVT
// (needs only Vb/hopWb, ready; hopVT consumed two launches later).
// ---------------------------------------------------------------------------
__global__ __launch_bounds__(256) void k_qksm(
    const u16* __restrict__ Qb, const u16* __restrict__ Kb,
    const float* __restrict__ btab, const float* __restrict__ temp,
    u16* __restrict__ A, u16* __restrict__ AT,
    const u16* __restrict__ Vb, const u16* __restrict__ hopWb,
    u16* __restrict__ hopVT)
{
    __shared__ __align__(16) u16 sbuf[2][128 * 64];   // 32 KB
    __shared__ float lred[4][16];
    int t = threadIdx.x, lane = t & 63, w = t >> 6;
    int bx = blockIdx.x;
    if (bx >= 512) {
        hopv_tile(Vb, hopWb, hopVT, (bx - 512) * 128, sbuf[0], sbuf[1]);
        return;
    }
    float* smf = (float*)sbuf;                        // 3969 floats = 15876 B
    int fr = lane & 15, q4 = lane >> 4;
    int z = bx >> 6;
    int rb = (bx & 63) << 4;                  // q-row base within batch
    for (int i = t; i < 3969; i += 256) smf[i] = btab[i];
    __syncthreads();
    float invt = 1.0f / fmaxf(temp[0], 0.1f);
    const long SD = (long)SS * DD;
    const long SSq = (long)SS * SS;
    const u16* qrow = Qb + (long)z * SD + (long)(rb + fr) * 64 + q4 * 8;
    v8s aq0 = *(const v8s*)(qrow);
    v8s aq1 = *(const v8s*)(qrow + 32);
    int ih[4], iw[4];
    #pragma unroll
    for (int r = 0; r < 4; r++) {
        int ii = rb + q4 * 4 + r;
        ih[r] = ii >> 5; iw[r] = ii & 31;
    }
    const u16* kb0 = Kb + (long)z * SD + q4 * 8;
    int c0 = w << 8;
    float ef[16][4];
    float l0 = 0.f, l1 = 0.f, l2 = 0.f, l3 = 0.f;
    #pragma unroll
    for (int f = 0; f < 16; f++) {
        int colK = c0 + f * 16 + fr;
        const u16* krow = kb0 + (long)colK * 64;
        v8s bk0 = *(const v8s*)(krow);
        v8s bk1 = *(const v8s*)(krow + 32);
        v4f acc = {0.f, 0.f, 0.f, 0.f};
        acc = __builtin_amdgcn_mfma_f32_16x16x32_bf16(aq0, bk0, acc, 0, 0, 0);
        acc = __builtin_amdgcn_mfma_f32_16x16x32_bf16(aq1, bk1, acc, 0, 0, 0);
        int jh = colK >> 5, jw = colK & 31;
        #pragma unroll
        for (int r = 0; r < 4; r++) {
            float pb = smf[(ih[r] - jh + 31) * 63 + (iw[r] - jw + 31)];
            float s = (acc[r] * 0.125f + pb) * invt;
            float e = __expf(s);
            ef[f][r] = e;
            if (r == 0) l0 += e; else if (r == 1) l1 += e;
            else if (r == 2) l2 += e; else l3 += e;
        }
    }
    #pragma unroll
    for (int o = 1; o < 16; o <<= 1) {
        l0 += __shfl_xor(l0, o); l1 += __shfl_xor(l1, o);
        l2 += __shfl_xor(l2, o); l3 += __shfl_xor(l3, o);
    }
    if (fr == 0) {
        lred[w][q4 * 4 + 0] = l0; lred[w][q4 * 4 + 1] = l1;
        lred[w][q4 * 4 + 2] = l2; lred[w][q4 * 4 + 3] = l3;
    }
    __syncthreads();
    float invl[4];
    #pragma unroll
    for (int r = 0; r < 4; r++) {
        int idx = q4 * 4 + r;
        invl[r] = 1.0f / (lred[0][idx] + lred[1][idx] + lred[2][idx] + lred[3][idx]);
    }
    u16* Ab = A + (long)z * SSq;
    u16* ATb = AT + (long)z * SSq;
    #pragma unroll
    for (int f = 0; f < 16; f++) {
        int colK = c0 + f * 16 + fr;
        ushort4 pv;
        u16* pp = (u16*)&pv;
        #pragma unroll
        for (int r = 0; r < 4; r++) {
            u16 bv = f2bf(ef[f][r] * invl[r]);
            pp[r] = bv;
            Ab[(long)(rb + q4 * 4 + r) * 1024 + colK] = bv;
        }
        *(ushort4*)(ATb + (long)colK * 1024 + rb + q4 * 4) = pv;
    }
}

// ---------------------------------------------------------------------------
// Generation-1: AAt (upper 36, reg-mirrored), AtA (same), A2 = A*A (full 64).
// 1D grid 1088 = 8 batches x 136 jobs, batch = blockIdx.x & 7 (XCD locality).
// ---------------------------------------------------------------------------
__global__ __launch_bounds__(256) void gemm_link1(
    const u16* __restrict__ A, const u16* __restrict__ AT,
    u16* __restrict__ AAt, u16* __restrict__ AtA, u16* __restrict__ A2)
{
    __shared__ u16 Xs[128 * 64];
    __shared__ u16 Ys[128 * 64];
    const long SSq = (long)SS * SS;
    int b = blockIdx.x & 7;
    int job = blockIdx.x >> 3;
    const u16* Xb; const u16* Yb; u16* Cd;
    int ti, tj, mir;
    if (job < 72) {
        int tt = job < 36 ? job : job - 36;
        ti = 0;
        while (tt >= 8 - ti) { tt -= 8 - ti; ti++; }
        tj = ti + tt;
        mir = (ti != tj);
        if (job < 36) { Xb = A  + b * SSq; Yb = Xb; Cd = AAt + b * SSq; }
        else          { Xb = AT + b * SSq; Yb = Xb; Cd = AtA + b * SSq; }
    } else {
        int jj = job - 72;
        ti = jj >> 3; tj = jj & 7; mir = 0;
        Xb = A + b * SSq; Yb = AT + b * SSq; Cd = A2 + b * SSq;   // A2 = A*(AT)^T = A*A
    }
    tile_1024(Xb, Yb, Cd, ti * 128, tj * 128, Xs, Ys, mir);
}

// ---------------------------------------------------------------------------
// MERGED: gen-2 symmetric pair (576 tile_1024 blocks, dispatched first) +
// fused hop-0 rows (2048 blocks).
// ---------------------------------------------------------------------------
__global__ __launch_bounds__(256) void k_link2_fused0(
    const u16* __restrict__ AAt, const u16* __restrict__ AtA,
    u16* __restrict__ AAt2, u16* __restrict__ AtA2,
    const u16* __restrict__ A, const float* __restrict__ fw,
    const float* __restrict__ fbv, u16* __restrict__ F0)
{
    __shared__ u16 Xs[128 * 64];
    __shared__ u16 Ys[128 * 64];
    const long SSq = (long)SS * SS;
    int bx = blockIdx.x;
    if (bx < 576) {
        int z = bx & 15;
        int tt = bx >> 4, ti = 0;
        while (tt >= 8 - ti) { tt -= 8 - ti; ti++; }
        int tj = ti + tt;
        const u16* Xb = (z < 8 ? AAt : AtA) + (long)(z & 7) * SSq;
        u16* Cd = (z < 8 ? AAt2 : AtA2) + (long)(z & 7) * SSq;
        tile_1024(Xb, Xb, Cd, ti * 128, tj * 128, Xs, Ys, ti != tj);
    } else {
        int lane = threadIdx.x & 63, w = threadIdx.x >> 6;
        float w0 = fw[0], w1 = fw[1], w2 = fw[2], b0 = fbv[0];
        long row = (long)(bx - 576) * 4 + w;
        fused_row(A + row * 1024, AAt + row * 1024, AtA + row * 1024,
                  w0, w1, w2, b0, F0 + row * 1024, lane);
    }
}

// ---------------------------------------------------------------------------
// MERGED: hop-0 GEMM tail (256 split-K blocks, dispatched first) + fused
// hop-1 rows (2048 blocks).
// ---------------------------------------------------------------------------
__global__ __launch_bounds__(256) void k_hop0_fused1(
    const u16* __restrict__ F0, const u16* __restrict__ hopVT,
    float* __restrict__ Pa, float* __restrict__ Pb,
    const u16* __restrict__ A2, const u16* __restrict__ AAt2,
    const u16* __restrict__ AtA2, const float* __restrict__ fw,
    const float* __restrict__ fbv, u16* __restrict__ F1)
{
    __shared__ u16 Fs[128 * 64];
    __shared__ u16 Hs[64 * 64];
    const long SSq = (long)SS * SS;
    int bx = blockIdx.x;
    if (bx < 256) {
        int y = bx >> 6, rest = bx & 63;
        int tmt = rest >> 3, b = rest & 7;
        float* Pd = (y < 2 ? Pa + (long)y * 16 * 65536 : Pb + (long)(y - 2) * 16 * 65536)
                    + (long)b * 65536;                    // hop=0
        hop_tile(F0 + (long)b * SSq, hopVT + (long)b * 65536, y, tmt, Pd, Fs, Hs);
    } else {
        int lane = threadIdx.x & 63, w = threadIdx.x >> 6;
        float w0 = fw[3], w1 = fw[4], w2 = fw[5], b0 = fbv[1];
        long row = (long)(bx - 256) * 4 + w;
        fused_row(A2 + row * 1024, AAt2 + row * 1024, AtA2 + row * 1024,
                  w0, w1, w2, b0, F1 + row * 1024, lane);
    }
}

// hop-1 GEMM standalone, split-K=4: grid 256.
__global__ __launch_bounds__(256) void gemm_hop1(
    const u16* __restrict__ F1, const u16* __restrict__ hopVT,
    float* __restrict__ Pa, float* __restrict__ Pb)
{
    __shared__ u16 Fs[128 * 64];
    __shared__ u16 Hs[64 * 64];
    const long SSq = (long)SS * SS;
    int j = blockIdx.x;
    int y = j >> 6, rest = j & 63;
    int tmt = rest >> 3, b = rest & 7;
    float* Pd = (y < 2 ? Pa + (long)y * 16 * 65536 : Pb + (long)(y - 2) * 16 * 65536)
                + (long)(8 + b) * 65536;                  // hop=1
    hop_tile(F1 + (long)b * SSq, hopVT + (long)(8 + b) * 65536, y, tmt, Pd, Fs, Hs);
}

// ---------------------------------------------------------------------------
// Generic batched NT GEMM (final projection): C[z] = X[z](MxK) * Y[z]^T(NxK)
// ---------------------------------------------------------------------------
__global__ __launch_bounds__(256) void gemm_nt(
    const u16* __restrict__ X, long sx,
    const u16* __restrict__ Y, long sy,
    void* __restrict__ Cv, long sc,
    int M, int N, int K, int cf32)
{
    __shared__ u16 Xs[128 * 64];
    __shared__ u16 Ys[128 * 64];
    const u16* Xb = X + (long)blockIdx.z * sx;
    const u16* Yb = Y + (long)blockIdx.z * sy;
    int tm = blockIdx.x * 128, tn = blockIdx.y * 128;
    int t = threadIdx.x, lane = t & 63, w = t >> 6;
    int wm = (w & 1) << 6, wn = (w >> 1) << 6;
    int fr = lane & 15, q = lane >> 4, m7 = fr & 7;
    int subrow = lane >> 3, cch = (lane & 7) ^ subrow;

    const u16* xg[4]; const u16* yg[4]; u16* xl[4]; u16* yl[4];
    #pragma unroll
    for (int i = 0; i < 4; i++) {
        int r = i * 32 + w * 8 + subrow;
        xg[i] = Xb + (long)(tm + r) * K + cch * 8;
        yg[i] = Yb + (long)(tn + r) * K + cch * 8;
        xl[i] = Xs + (i * 32 + w * 8) * 64;
        yl[i] = Ys + (i * 32 + w * 8) * 64;
    }

    v4f acc[4][4];
    #pragma unroll
    for (int i = 0; i < 4; i++)
        #pragma unroll
        for (int j = 0; j < 4; j++) {
            acc[i][j][0] = 0.f; acc[i][j][1] = 0.f; acc[i][j][2] = 0.f; acc[i][j][3] = 0.f;
        }

    for (int k0 = 0; k0 < K; k0 += 64) {
        __syncthreads();
        #pragma unroll
        for (int i = 0; i < 4; i++) { gload16(xg[i] + k0, xl[i]); gload16(yg[i] + k0, yl[i]); }
        __syncthreads();
        v8s af[2][4], bfr[2][4];
        #pragma unroll
        for (int h = 0; h < 2; h++) {
            int ca = (((h << 2) + q) ^ m7) << 3;
            #pragma unroll
            for (int s = 0; s < 4; s++) {
                af[h][s]  = *(const v8s*)(Xs + (wm + s * 16 + fr) * 64 + ca);
                bfr[h][s] = *(const v8s*)(Ys + (wn + s * 16 + fr) * 64 + ca);
            }
        }
        #pragma unroll
        for (int h = 0; h < 2; h++)
            #pragma unroll
            for (int i = 0; i < 4; i++)
                #pragma unroll
                for (int j = 0; j < 4; j++)
                    acc[i][j] = __builtin_amdgcn_mfma_f32_16x16x32_bf16(af[h][i], bfr[h][j], acc[i][j], 0, 0, 0);
    }
    long cb = (long)blockIdx.z * sc;
    #pragma unroll
    for (int i = 0; i < 4; i++) {
        int rowb = tm + wm + i * 16 + q * 4;
        #pragma unroll
        for (int j = 0; j < 4; j++) {
            int col = tn + wn + j * 16 + fr;
            #pragma unroll
            for (int r = 0; r < 4; r++) {
                long o = cb + (long)(rowb + r) * N + col;
                if (cf32) ((float*)Cv)[o] = acc[i][j][r];
                else      ((u16*)Cv)[o] = f2bf(acc[i][j][r]);
            }
        }
    }
}

// ---------------------------------------------------------------------------
// Projection GEMM reading x DIRECTLY in fp32 (reg-staged conversion, same RNE
// f2bf as the old pack — numerics identical). 512 threads, 128x256 tile,
// grid 64: x read ONCE, xb + the 4096-block x-pack are gone.
// Wave roles by wn: 0=Q(rope), 64=K(rope), 128=V, 192=gate.
// X staging emulates gload16's lane->LDS layout so ds_read side is unchanged.
// ---------------------------------------------------------------------------
__global__ __launch_bounds__(512) void k_proj_rope(
    const float* __restrict__ x, const u16* __restrict__ wpack,
    const float* __restrict__ gateb, const float2* __restrict__ ropetab,
    u16* __restrict__ Qb, u16* __restrict__ Kb, u16* __restrict__ Vb,
    float* __restrict__ gate)
{
    __shared__ u16 Xs[128 * 64];
    __shared__ u16 Ys[256 * 64];
    int tm = blockIdx.x * 128;
    int t = threadIdx.x, lane = t & 63, w = t >> 6;          // w in 0..7
    int wm = (w & 1) << 6, wn = (w >> 1) << 6;               // wn in {0,64,128,192}
    int fr = lane & 15, q = lane >> 4, m7 = fr & 7;
    int subrow = lane >> 3, cch = (lane & 7) ^ subrow;

    // Y (wpack, bf16): 4 gload16 per thread cover 256 rows.
    const u16* yg[4]; u16* yl[4];
    #pragma unroll
    for (int i = 0; i < 4; i++) {
        int r = i * 64 + w * 8 + subrow;
        yg[i] = wpack + (long)r * 512 + cch * 8;
        yl[i] = Ys + (i * 64 + w * 8) * 64;
    }
    // X (x, fp32 -> bf16 in regs): 2 rows-groups per thread cover 128 rows.
    const float* xg[2]; u16* xw[2];
    #pragma unroll
    for (int i = 0; i < 2; i++) {
        int r = i * 64 + w * 8 + subrow;
        xg[i] = x + (long)(tm + r) * 512 + cch * 8;
        xw[i] = Xs + r * 64 + (lane & 7) * 8;
    }

    v4f acc[4][4];
    #pragma unroll
    for (int i = 0; i < 4; i++)
        #pragma unroll
        for (int j = 0; j < 4; j++) {
            acc[i][j][0] = 0.f; acc[i][j][1] = 0.f; acc[i][j][2] = 0.f; acc[i][j][3] = 0.f;
        }

    for (int k0 = 0; k0 < 512; k0 += 64) {
        __syncthreads();
        #pragma unroll
        for (int i = 0; i < 4; i++) gload16(yg[i] + k0, yl[i]);
        #pragma unroll
        for (int i = 0; i < 2; i++) {
            float4 v0 = *(const float4*)(xg[i] + k0);
            float4 v1 = *(const float4*)(xg[i] + k0 + 4);
            v8s pk;
            pk[0] = (short)f2bf(v0.x); pk[1] = (short)f2bf(v0.y);
            pk[2] = (short)f2bf(v0.z); pk[3] = (short)f2bf(v0.w);
            pk[4] = (short)f2bf(v1.x); pk[5] = (short)f2bf(v1.y);
            pk[6] = (short)f2bf(v1.z); pk[7] = (short)f2bf(v1.w);
            *(v8s*)xw[i] = pk;
        }
        __syncthreads();
        v8s af[2][4], bfr[2][4];
        #pragma unroll
        for (int h = 0; h < 2; h++) {
            int ca = (((h << 2) + q) ^ m7) << 3;
            #pragma unroll
            for (int s = 0; s < 4; s++) {
                af[h][s]  = *(const v8s*)(Xs + (wm + s * 16 + fr) * 64 + ca);
                bfr[h][s] = *(const v8s*)(Ys + (wn + s * 16 + fr) * 64 + ca);
            }
        }
        #pragma unroll
        for (int h = 0; h < 2; h++)
            #pragma unroll
            for (int i = 0; i < 4; i++)
                #pragma unroll
                for (int j = 0; j < 4; j++)
                    acc[i][j] = __builtin_amdgcn_mfma_f32_16x16x32_bf16(af[h][i], bfr[h][j], acc[i][j], 0, 0, 0);
    }

    if (wn < 128) {
        // Q (wn=0) or K (wn=64): rope. col l = j*16+fr; partner l^32 = acc[i][j^2][r].
        u16* dst = wn ? Kb : Qb;
        #pragma unroll
        for (int i = 0; i < 4; i++) {
            #pragma unroll
            for (int r = 0; r < 4; r++) {
                int row = tm + wm + i * 16 + q * 4 + r;
                int spos = row & (SS - 1);
                float2 t0 = ropetab[spos * 32 + fr];        // f = fr   (j even)
                float2 t1 = ropetab[spos * 32 + 16 + fr];   // f = fr+16 (j odd)
                #pragma unroll
                for (int j = 0; j < 4; j++) {
                    float v = acc[i][j][r], p = acc[i][j ^ 2][r];
                    float cs = (j & 1) ? t1.x : t0.x;
                    float sn = (j & 1) ? t1.y : t0.y;
                    float o = (j & 2) ? (v * cs + p * sn) : (v * cs - p * sn);
                    dst[(long)row * 64 + j * 16 + fr] = f2bf(o);
                }
            }
        }
    } else if (wn == 128) {
        // V: col l = j*16+fr
        #pragma unroll
        for (int i = 0; i < 4; i++)
            #pragma unroll
            for (int j = 0; j < 4; j++)
                #pragma unroll
                for (int r = 0; r < 4; r++) {
                    int row = tm + wm + i * 16 + q * 4 + r;
                    Vb[(long)row * 64 + j * 16 + fr] = f2bf(acc[i][j][r]);
                }
    } else {
        // gate: global cols 192/193 = j=0, fr in {0,1}
        float gb = gateb[fr & 1];
        #pragma unroll
        for (int i = 0; i < 4; i++)
            #pragma unroll
            for (int r = 0; r < 4; r++) {
                int row = tm + wm + i * 16 + q * 4 + r;
                float g = acc[i][0][r] + gb;
                float go = __shfl_xor(g, 1);
                float m = fmaxf(g, go);
                float e = __expf(g - m), eo = __expf(go - m);
                if (fr < 2) gate[(long)row * 2 + fr] = e / (e + eo);
            }
    }
}

// pack weights to bf16 + rope cos/sin table (x-pack removed: proj reads x).
__global__ __launch_bounds__(256) void k_pack(
    const float* __restrict__ Wq, const float* __restrict__ Wk,
    const float* __restrict__ Wv, const float* __restrict__ gW,
    const float* __restrict__ hopW, const float* __restrict__ outW,
    u16* __restrict__ wpack, u16* __restrict__ hopWb, u16* __restrict__ outWb,
    float2* __restrict__ ropetab)
{
    int bx = blockIdx.x;
    if (bx < 672) {
        int idx = bx * 256 + threadIdx.x;
        if (idx < 131072) {
            int r = idx >> 9, c = idx & 511;
            float v = 0.f;
            if (r < 64)       v = Wq[r * 512 + c];
            else if (r < 128) v = Wk[(r - 64) * 512 + c];
            else if (r < 192) v = Wv[(r - 128) * 512 + c];
            else if (r < 194) v = gW[(r - 192) * 512 + c];
            wpack[idx] = f2bf(v);
        } else if (idx < 131072 + 8192) {
            int i = idx - 131072;
            hopWb[i] = f2bf(hopW[i]);
        } else if (idx < 131072 + 8192 + 32768) {
            int i = idx - 131072 - 8192;
            outWb[i] = f2bf(outW[i]);
        }
    } else {
        int idx = (bx - 672) * 256 + threadIdx.x;   // 0..32767
        int spos = idx >> 5, f = idx & 31;
        float ang = (float)spos * exp2f(-(float)f * (13.287712379549449f / 32.0f));
        float sn, cs;
        sincosf(ang, &sn, &cs);
        ropetab[idx] = make_float2(cs, sn);
    }
}

// sum split-K=4 partials, gate-combine -> comb bf16 [8192][64]
__global__ __launch_bounds__(256) void k_combine(
    const float* __restrict__ Pa, const float* __restrict__ Pb,
    const float* __restrict__ gate, u16* __restrict__ comb)
{
    long idx = (long)blockIdx.x * 256 + threadIdx.x;   // 8192*64
    long srow = idx >> 6;
    int b = (int)(srow >> 10);
    long o = (long)(srow & 1023) * 64 + (idx & 63);
    float h0 = Pa[(long)b * 65536 + o] + Pa[(long)(16 + b) * 65536 + o]
             + Pb[(long)b * 65536 + o] + Pb[(long)(16 + b) * 65536 + o];
    float h1 = Pa[(long)(8 + b) * 65536 + o] + Pa[(long)(24 + b) * 65536 + o]
             + Pb[(long)(8 + b) * 65536 + o] + Pb[(long)(24 + b) * 65536 + o];
    float g0 = gate[srow * 2], g1 = gate[srow * 2 + 1];
    comb[idx] = f2bf(h0 * g0 + h1 * g1);
}

// ---------------------------------------------------------------------------
extern "C" void kernel_launch(void* const* d_in, const int* in_sizes, int n_in,
                              void* d_out, int out_size, void* d_ws, size_t ws_size,
                              hipStream_t stream) {
    const float* x    = (const float*)d_in[0];
    const float* Wq   = (const float*)d_in[1];
    const float* Wk   = (const float*)d_in[2];
    const float* Wv   = (const float*)d_in[3];
    const float* btab = (const float*)d_in[4];
    const float* fw   = (const float*)d_in[5];
    const float* fbv  = (const float*)d_in[6];
    const float* hopW = (const float*)d_in[7];
    const float* gW   = (const float*)d_in[8];
    const float* gb   = (const float*)d_in[9];
    const float* outW = (const float*)d_in[10];
    const float* temp = (const float*)d_in[11];
    float* out = (float*)d_out;

    char* wsb = (char*)d_ws;
    size_t off = 0;
    auto take = [&](size_t n) { char* p = wsb + off; off += (n + 255) & ~(size_t)255; return p; };
    u16* Qb      = (u16*)take(8192L * 64 * 2);
    u16* Kb      = (u16*)take(8192L * 64 * 2);
    u16* Vb      = (u16*)take(8192L * 64 * 2);
    float* gate  = (float*)take(8192L * 2 * 4);
    u16* wpack   = (u16*)take(256L * 512 * 2);
    u16* hopWb   = (u16*)take(2L * 64 * 64 * 2);
    u16* outWb   = (u16*)take(512L * 64 * 2);
    float2* ropetab = (float2*)take(1024L * 32 * 8);
    u16* hopVT   = (u16*)take(2L * 8 * 64 * 1024 * 2);
    float* Pa    = (float*)take(2L * 16 * 65536 * 4);     // split-K partials y=0,1
    u16* comb    = (u16*)take(8192L * 64 * 2);
    char* fregion = take(8L * 1024 * 1024 * 4);       // 32 MB region for F0/F1
    u16* F0      = (u16*)fregion;
    u16* F1      = (u16*)fregion + 8L * 1024 * 1024;  // second 16 MB of region
    u16* A       = (u16*)take(8L * 1024 * 1024 * 2);
    u16* AT      = (u16*)take(8L * 1024 * 1024 * 2);
    float* Pb    = (float*)AT;                        // alias: AT dead after link1
    u16* AAt     = (u16*)take(8L * 1024 * 1024 * 2);
    u16* AtA     = (u16*)take(8L * 1024 * 1024 * 2);
    u16* A2      = (u16*)take(8L * 1024 * 1024 * 2);
    u16* AAt2    = (u16*)take(8L * 1024 * 1024 * 2);
    u16* AtA2    = (u16*)take(8L * 1024 * 1024 * 2);
    (void)ws_size; (void)in_sizes; (void)n_in; (void)out_size;

    // 1. pack weights + rope table (x-pack eliminated)
    k_pack<<<800, 256, 0, stream>>>(Wq, Wk, Wv, gW, hopW, outW, wpack,
                                    hopWb, outWb, ropetab);
    // 2. projection GEMM reading x directly + fused rope + gate softmax
    k_proj_rope<<<64, 512, 0, stream>>>(x, wpack, gb, ropetab,
                                        Qb, Kb, Vb, gate);
    // 3. fused QK^T + softmax -> A, AT + hopV rider -> hopVT
    k_qksm<<<576, 256, 0, stream>>>(Qb, Kb, btab, temp, A, AT, Vb, hopWb, hopVT);
    // 4. generation-1: AAt, AtA (reg-mirrored) + A2
    gemm_link1<<<1088, 256, 0, stream>>>(A, AT, AAt, AtA, A2);
    // 5. gen-2 sym pair (576 GEMM blocks first) + fused hop-0 rows (2048)
    k_link2_fused0<<<2624, 256, 0, stream>>>(AAt, AtA, AAt2, AtA2, A, fw, fbv, F0);
    // 6. hop-0 GEMM tail (256 first) + fused hop-1 rows (2048)
    k_hop0_fused1<<<2304, 256, 0, stream>>>(F0, hopVT, Pa, Pb, A2, AAt2, AtA2,
                                            fw, fbv, F1);
    // 7. hop-1 GEMM
    gemm_hop1<<<256, 256, 0, stream>>>(F1, hopVT, Pa, Pb);
    // 8. combine + output projection
    k_combine<<<2048, 256, 0, stream>>>(Pa, Pb, gate, comb);
    gemm_nt<<<dim3(64, 4, 1), 256, 0, stream>>>(comb, 0, outWb, 0, out, 0, 8192, 512, 64, 1);
}

// Round 5
// 277.277 us; speedup vs baseline: 1.0362x; 1.0362x over previous
//
#include <hip/hip_runtime.h>
#include <hip/hip_bf16.h>

// Problem constants
#define BB 8
#define SS 1024
#define HH 512
#define DD 64

typedef unsigned short u16;
typedef short v8s __attribute__((ext_vector_type(8)));   // 8 x bf16 (bit pattern)
typedef float v4f __attribute__((ext_vector_type(4)));

__device__ __forceinline__ float bf2f(u16 u) {
    union { unsigned int i; float f; } v; v.i = ((unsigned int)u) << 16; return v.f;
}
__device__ __forceinline__ u16 f2bf(float f) {
    union { float f; unsigned int i; } v; v.f = f;
    unsigned int u = v.i;
    unsigned int r = u + 0x7fffu + ((u >> 16) & 1u);   // RNE
    return (u16)(r >> 16);
}

// async 16B global->LDS DMA: lane L's data lands at ldsbase + L*16
__device__ __forceinline__ void gload16(const u16* g, u16* l) {
    __builtin_amdgcn_global_load_lds(
        (const __attribute__((address_space(1))) void*)g,
        (__attribute__((address_space(3))) void*)l,
        16, 0, 0);
}

// ---------------------------------------------------------------------------
// Shared GEMM geometry (BK=64): LDS rows of 64 bf16 = 8 chunks of 16B.
// Physical chunk p of row r holds logical chunk p ^ (r&7) (conflict-free b128).
// Staging: thread t=64w+lane, instr i: row = i*32 + w*8 + (lane>>3),
//          phys chunk = lane&7, global col chunk = (lane&7) ^ (lane>>3).
//
// tile_1024: 128x128 tile x K=1024 NT product, bf16 out. mirror!=0 (symmetric
// product, off-diagonal tile): ALSO writes C[tn..][tm..] = tile^T directly
// from registers — C-layout gives each lane 4 consecutive rows of one column,
// i.e. 4 consecutive u16 of the transposed tile -> one packed 8B store.
// ---------------------------------------------------------------------------
__device__ __forceinline__ void tile_1024(
    const u16* __restrict__ Xb, const u16* __restrict__ Yb,
    u16* __restrict__ Cd, int tm, int tn, u16* Xs, u16* Ys, int mirror)
{
    int t = threadIdx.x, lane = t & 63, w = t >> 6;
    int wm = (w & 1) << 6, wn = (w >> 1) << 6;
    int fr = lane & 15, q = lane >> 4, m7 = fr & 7;
    int subrow = lane >> 3, cch = (lane & 7) ^ subrow;

    const u16* xg[4]; const u16* yg[4]; u16* xl[4]; u16* yl[4];
    #pragma unroll
    for (int i = 0; i < 4; i++) {
        int r = i * 32 + w * 8 + subrow;
        xg[i] = Xb + (long)(tm + r) * 1024 + cch * 8;
        yg[i] = Yb + (long)(tn + r) * 1024 + cch * 8;
        xl[i] = Xs + (i * 32 + w * 8) * 64;
        yl[i] = Ys + (i * 32 + w * 8) * 64;
    }

    v4f acc[4][4];
    #pragma unroll
    for (int i = 0; i < 4; i++)
        #pragma unroll
        for (int j = 0; j < 4; j++) {
            acc[i][j][0] = 0.f; acc[i][j][1] = 0.f; acc[i][j][2] = 0.f; acc[i][j][3] = 0.f;
        }

    for (int k0 = 0; k0 < 1024; k0 += 64) {
        __syncthreads();
        #pragma unroll
        for (int i = 0; i < 4; i++) { gload16(xg[i] + k0, xl[i]); gload16(yg[i] + k0, yl[i]); }
        __syncthreads();
        v8s af[2][4], bfr[2][4];
        #pragma unroll
        for (int h = 0; h < 2; h++) {
            int ca = (((h << 2) + q) ^ m7) << 3;
            #pragma unroll
            for (int s = 0; s < 4; s++) {
                af[h][s]  = *(const v8s*)(Xs + (wm + s * 16 + fr) * 64 + ca);
                bfr[h][s] = *(const v8s*)(Ys + (wn + s * 16 + fr) * 64 + ca);
            }
        }
        #pragma unroll
        for (int h = 0; h < 2; h++)
            #pragma unroll
            for (int i = 0; i < 4; i++)
                #pragma unroll
                for (int j = 0; j < 4; j++)
                    acc[i][j] = __builtin_amdgcn_mfma_f32_16x16x32_bf16(af[h][i], bfr[h][j], acc[i][j], 0, 0, 0);
    }
    #pragma unroll
    for (int i = 0; i < 4; i++) {
        int rowb = tm + wm + i * 16 + q * 4;
        #pragma unroll
        for (int j = 0; j < 4; j++) {
            int col = tn + wn + j * 16 + fr;
            ushort4 pv;
            pv.x = f2bf(acc[i][j][0]); pv.y = f2bf(acc[i][j][1]);
            pv.z = f2bf(acc[i][j][2]); pv.w = f2bf(acc[i][j][3]);
            #pragma unroll
            for (int r = 0; r < 4; r++)
                Cd[(long)(rowb + r) * 1024 + col] = ((u16*)&pv)[r];
            if (mirror)   // transposed tile: 4 consecutive u16 at row=col
                *(ushort4*)(Cd + (long)col * 1024 + rowb) = pv;
        }
    }
}

// ---------------------------------------------------------------------------
// hopV projection tile (K=64, 128 rows of V x 128 rows of hopWb), writing the
// TRANSPOSED result directly to hopVT[(hop*8+z)][e][s]: each lane's acc[i][j]
// holds 4 consecutive s-rows of one e-column -> one packed 8B store.
// ---------------------------------------------------------------------------
__device__ __forceinline__ void hopv_tile(
    const u16* __restrict__ Vrows, const u16* __restrict__ Hw,
    u16* __restrict__ hopVT, int tm, u16* Xs, u16* Ys)
{
    int t = threadIdx.x, lane = t & 63, w = t >> 6;
    int wm = (w & 1) << 6, wn = (w >> 1) << 6;
    int fr = lane & 15, q = lane >> 4, m7 = fr & 7;
    int subrow = lane >> 3, cch = (lane & 7) ^ subrow;

    #pragma unroll
    for (int i = 0; i < 4; i++) {
        int r = i * 32 + w * 8 + subrow;
        gload16(Vrows + (long)(tm + r) * 64 + cch * 8, Xs + (i * 32 + w * 8) * 64);
        gload16(Hw + (long)r * 64 + cch * 8, Ys + (i * 32 + w * 8) * 64);
    }
    __syncthreads();

    v4f acc[4][4];
    #pragma unroll
    for (int i = 0; i < 4; i++)
        #pragma unroll
        for (int j = 0; j < 4; j++) {
            acc[i][j][0] = 0.f; acc[i][j][1] = 0.f; acc[i][j][2] = 0.f; acc[i][j][3] = 0.f;
        }
    v8s af[2][4], bfr[2][4];
    #pragma unroll
    for (int h = 0; h < 2; h++) {
        int ca = (((h << 2) + q) ^ m7) << 3;
        #pragma unroll
        for (int s = 0; s < 4; s++) {
            af[h][s]  = *(const v8s*)(Xs + (wm + s * 16 + fr) * 64 + ca);
            bfr[h][s] = *(const v8s*)(Ys + (wn + s * 16 + fr) * 64 + ca);
        }
    }
    #pragma unroll
    for (int h = 0; h < 2; h++)
        #pragma unroll
        for (int i = 0; i < 4; i++)
            #pragma unroll
            for (int j = 0; j < 4; j++)
                acc[i][j] = __builtin_amdgcn_mfma_f32_16x16x32_bf16(af[h][i], bfr[h][j], acc[i][j], 0, 0, 0);

    int z = tm >> 10, sb = tm & 1023;
    #pragma unroll
    for (int i = 0; i < 4; i++) {
        int rowb = wm + i * 16 + q * 4;
        #pragma unroll
        for (int j = 0; j < 4; j++) {
            int colY = wn + j * 16 + fr;
            int hop = colY >> 6, e = colY & 63;
            ushort4 pv;
            pv.x = f2bf(acc[i][j][0]); pv.y = f2bf(acc[i][j][1]);
            pv.z = f2bf(acc[i][j][2]); pv.w = f2bf(acc[i][j][3]);
            *(ushort4*)(hopVT + (long)(hop * 8 + z) * 65536 + (long)e * 1024 + sb + rowb) = pv;
        }
    }
}

// 128x64 F@H^T tile over K-range [y*256,(y+1)*256). Fs:128x64, Hs:64x64 LDS.
__device__ __forceinline__ void hop_tile(
    const u16* __restrict__ Fb, const u16* __restrict__ Hb,
    int y, int tmt, float* __restrict__ Pd, u16* Fs, u16* Hs)
{
    int tm = tmt * 128, kb = y * 256;
    int t = threadIdx.x, lane = t & 63, w = t >> 6;
    int fr = lane & 15, q = lane >> 4, m7 = fr & 7;
    int subrow = lane >> 3, cch = (lane & 7) ^ subrow;

    const u16* fg[4]; u16* fl[4]; const u16* hg[2]; u16* hl[2];
    #pragma unroll
    for (int i = 0; i < 4; i++) {
        int r = i * 32 + w * 8 + subrow;
        fg[i] = Fb + (long)(tm + r) * 1024 + cch * 8;
        fl[i] = Fs + (i * 32 + w * 8) * 64;
    }
    #pragma unroll
    for (int i = 0; i < 2; i++) {
        int r = i * 32 + w * 8 + subrow;
        hg[i] = Hb + (long)r * 1024 + cch * 8;
        hl[i] = Hs + (i * 32 + w * 8) * 64;
    }

    v4f acc[2][4];
    #pragma unroll
    for (int i = 0; i < 2; i++)
        #pragma unroll
        for (int j = 0; j < 4; j++) {
            acc[i][j][0] = 0.f; acc[i][j][1] = 0.f; acc[i][j][2] = 0.f; acc[i][j][3] = 0.f;
        }

    for (int k0 = kb; k0 < kb + 256; k0 += 64) {
        __syncthreads();
        #pragma unroll
        for (int i = 0; i < 4; i++) gload16(fg[i] + k0, fl[i]);
        #pragma unroll
        for (int i = 0; i < 2; i++) gload16(hg[i] + k0, hl[i]);
        __syncthreads();
        v8s af[2][2], bfr[2][4];
        #pragma unroll
        for (int h = 0; h < 2; h++) {
            int ca = (((h << 2) + q) ^ m7) << 3;
            #pragma unroll
            for (int s = 0; s < 2; s++)
                af[h][s] = *(const v8s*)(Fs + (w * 32 + s * 16 + fr) * 64 + ca);
            #pragma unroll
            for (int s = 0; s < 4; s++)
                bfr[h][s] = *(const v8s*)(Hs + (s * 16 + fr) * 64 + ca);
        }
        #pragma unroll
        for (int h = 0; h < 2; h++)
            #pragma unroll
            for (int i = 0; i < 2; i++)
                #pragma unroll
                for (int j = 0; j < 4; j++)
                    acc[i][j] = __builtin_amdgcn_mfma_f32_16x16x32_bf16(af[h][i], bfr[h][j], acc[i][j], 0, 0, 0);
    }
    #pragma unroll
    for (int i = 0; i < 2; i++) {
        int rowb = tm + w * 32 + i * 16 + q * 4;
        #pragma unroll
        for (int j = 0; j < 4; j++) {
            int col = j * 16 + fr;
            #pragma unroll
            for (int r = 0; r < 4; r++)
                Pd[(long)(rowb + r) * 64 + col] = acc[i][j][r];
        }
    }
}

// fused prob_log/sigmoid/row-norm for one row (wave-collective, 64 lanes).
__device__ __forceinline__ void fused_row(
    const u16* __restrict__ r1, const u16* __restrict__ r2, const u16* __restrict__ r3,
    float w0, float w1, float w2, float b0, u16* __restrict__ Frow, int lane)
{
    int base = lane << 4;
    union U { uint4 v; u16 s[8]; };
    U a[2], b[2], c[2];
    a[0].v = *(const uint4*)(r1 + base); a[1].v = *(const uint4*)(r1 + base + 8);
    b[0].v = *(const uint4*)(r2 + base); b[1].v = *(const uint4*)(r2 + base + 8);
    c[0].v = *(const uint4*)(r3 + base); c[1].v = *(const uint4*)(r3 + base + 8);
    float m1[16], m2[16], m3[16];
    float s1 = 0.f, s2 = 0.f, s3 = 0.f;
    #pragma unroll
    for (int h = 0; h < 2; h++)
        #pragma unroll
        for (int e = 0; e < 8; e++) {
            int k = h * 8 + e;
            m1[k] = bf2f(a[h].s[e]); m2[k] = bf2f(b[h].s[e]); m3[k] = bf2f(c[h].s[e]);
            s1 += m1[k]; s2 += m2[k]; s3 += m3[k];
        }
    #pragma unroll
    for (int o = 1; o < 64; o <<= 1) {
        s1 += __shfl_xor(s1, o); s2 += __shfl_xor(s2, o); s3 += __shfl_xor(s3, o);
    }
    float i1 = 1.f / (s1 + 1e-6f), i2 = 1.f / (s2 + 1e-6f), i3 = 1.f / (s3 + 1e-6f);
    float sig[16];
    float ssum = 0.f;
    #pragma unroll
    for (int k = 0; k < 16; k++) {
        float p1 = fminf(fmaxf(m1[k] * i1, 1e-6f), 1.0f - 1e-6f);
        float p2 = fminf(fmaxf(m2[k] * i2, 1e-6f), 1.0f - 1e-6f);
        float p3 = fminf(fmaxf(m3[k] * i3, 1e-6f), 1.0f - 1e-6f);
        float l1 = __logf(p1 / (1.0f - p1 + 1e-6f));
        float l2 = __logf(p2 / (1.0f - p2 + 1e-6f));
        float l3 = __logf(p3 / (1.0f - p3 + 1e-6f));
        float lg = b0 + w0 * l1 + w1 * l2 + w2 * l3;
        float sg = 1.0f / (1.0f + __expf(-lg));
        sig[k] = sg; ssum += sg;
    }
    #pragma unroll
    for (int o = 1; o < 64; o <<= 1) ssum += __shfl_xor(ssum, o);
    float inv = 1.0f / (ssum + 1e-6f);
    U o0, o1;
    #pragma unroll
    for (int e = 0; e < 8; e++) { o0.s[e] = f2bf(sig[e] * inv); o1.s[e] = f2bf(sig[8 + e] * inv); }
    *(uint4*)(Frow + base) = o0.v;
    *(uint4*)(Frow + base + 8) = o1.v;
}

// ---------------------------------------------------------------------------
// Fused QK^T + bias + temperature + softmax -> A and AT. No-max softmax:
// |scores| <= ~50 even at the temp clip floor, fp32 exp is exact-safe to 88.
// 512 blocks x 256 thr; block = 16 q-rows of batch z = bx>>6. Wave w covers
// k-cols [w*256,(w+1)*256). A/B fragments read DIRECTLY from global (K-panel
// is 128 KB/batch, L2-resident). Score frags stay in registers (ef[16][4]),
// one MFMA pass; row-sum via shfl + tiny LDS; then normalize + store.
// AT store: C-layout gives 4 consecutive rows of one col -> packed 8B store.
// ---------------------------------------------------------------------------
__global__ __launch_bounds__(256) void k_qksm(
    const u16* __restrict__ Qb, const u16* __restrict__ Kb,
    const float* __restrict__ btab, const float* __restrict__ temp,
    u16* __restrict__ A, u16* __restrict__ AT)
{
    __shared__ __align__(16) float smf[3969];
    __shared__ float lred[4][16];
    int t = threadIdx.x, lane = t & 63, w = t >> 6;
    int fr = lane & 15, q4 = lane >> 4;
    int bx = blockIdx.x;
    int z = bx >> 6;
    int rb = (bx & 63) << 4;                  // q-row base within batch
    for (int i = t; i < 3969; i += 256) smf[i] = btab[i];
    __syncthreads();
    float invt = 1.0f / fmaxf(temp[0], 0.1f);
    const long SD = (long)SS * DD;
    const long SSq = (long)SS * SS;
    const u16* qrow = Qb + (long)z * SD + (long)(rb + fr) * 64 + q4 * 8;
    v8s aq0 = *(const v8s*)(qrow);
    v8s aq1 = *(const v8s*)(qrow + 32);
    int ih[4], iw[4];
    #pragma unroll
    for (int r = 0; r < 4; r++) {
        int ii = rb + q4 * 4 + r;
        ih[r] = ii >> 5; iw[r] = ii & 31;
    }
    const u16* kb0 = Kb + (long)z * SD + q4 * 8;
    int c0 = w << 8;
    float ef[16][4];
    float l0 = 0.f, l1 = 0.f, l2 = 0.f, l3 = 0.f;
    #pragma unroll
    for (int f = 0; f < 16; f++) {
        int colK = c0 + f * 16 + fr;
        const u16* krow = kb0 + (long)colK * 64;
        v8s bk0 = *(const v8s*)(krow);
        v8s bk1 = *(const v8s*)(krow + 32);
        v4f acc = {0.f, 0.f, 0.f, 0.f};
        acc = __builtin_amdgcn_mfma_f32_16x16x32_bf16(aq0, bk0, acc, 0, 0, 0);
        acc = __builtin_amdgcn_mfma_f32_16x16x32_bf16(aq1, bk1, acc, 0, 0, 0);
        int jh = colK >> 5, jw = colK & 31;
        #pragma unroll
        for (int r = 0; r < 4; r++) {
            float pb = smf[(ih[r] - jh + 31) * 63 + (iw[r] - jw + 31)];
            float s = (acc[r] * 0.125f + pb) * invt;
            float e = __expf(s);
            ef[f][r] = e;
            if (r == 0) l0 += e; else if (r == 1) l1 += e;
            else if (r == 2) l2 += e; else l3 += e;
        }
    }
    #pragma unroll
    for (int o = 1; o < 16; o <<= 1) {
        l0 += __shfl_xor(l0, o); l1 += __shfl_xor(l1, o);
        l2 += __shfl_xor(l2, o); l3 += __shfl_xor(l3, o);
    }
    if (fr == 0) {
        lred[w][q4 * 4 + 0] = l0; lred[w][q4 * 4 + 1] = l1;
        lred[w][q4 * 4 + 2] = l2; lred[w][q4 * 4 + 3] = l3;
    }
    __syncthreads();
    float invl[4];
    #pragma unroll
    for (int r = 0; r < 4; r++) {
        int idx = q4 * 4 + r;
        invl[r] = 1.0f / (lred[0][idx] + lred[1][idx] + lred[2][idx] + lred[3][idx]);
    }
    u16* Ab = A + (long)z * SSq;
    u16* ATb = AT + (long)z * SSq;
    #pragma unroll
    for (int f = 0; f < 16; f++) {
        int colK = c0 + f * 16 + fr;
        ushort4 pv;
        u16* pp = (u16*)&pv;
        #pragma unroll
        for (int r = 0; r < 4; r++) {
            u16 bv = f2bf(ef[f][r] * invl[r]);
            pp[r] = bv;
            Ab[(long)(rb + q4 * 4 + r) * 1024 + colK] = bv;
        }
        *(ushort4*)(ATb + (long)colK * 1024 + rb + q4 * 4) = pv;
    }
}

// ---------------------------------------------------------------------------
// Generation-1: AAt (upper 36, reg-mirrored), AtA (same), A2 = A*A (full 64).
// blocks 0..1087: 8 batches x 136 jobs, batch = blockIdx.x & 7 (XCD locality).
// blocks 1088..1151: hopV projection rider (64 blocks) -> hopVT direct.
// ---------------------------------------------------------------------------
__global__ __launch_bounds__(256) void gemm_link1(
    const u16* __restrict__ A, const u16* __restrict__ AT,
    u16* __restrict__ AAt, u16* __restrict__ AtA, u16* __restrict__ A2,
    const u16* __restrict__ Vb, const u16* __restrict__ hopWb,
    u16* __restrict__ hopVT)
{
    __shared__ u16 Xs[128 * 64];
    __shared__ u16 Ys[128 * 64];
    const long SSq = (long)SS * SS;
    if (blockIdx.x >= 1088) {
        hopv_tile(Vb, hopWb, hopVT, (blockIdx.x - 1088) * 128, Xs, Ys);
        return;
    }
    int b = blockIdx.x & 7;
    int job = blockIdx.x >> 3;
    const u16* Xb; const u16* Yb; u16* Cd;
    int ti, tj, mir;
    if (job < 72) {
        int tt = job < 36 ? job : job - 36;
        ti = 0;
        while (tt >= 8 - ti) { tt -= 8 - ti; ti++; }
        tj = ti + tt;
        mir = (ti != tj);
        if (job < 36) { Xb = A  + b * SSq; Yb = Xb; Cd = AAt + b * SSq; }
        else          { Xb = AT + b * SSq; Yb = Xb; Cd = AtA + b * SSq; }
    } else {
        int jj = job - 72;
        ti = jj >> 3; tj = jj & 7; mir = 0;
        Xb = A + b * SSq; Yb = AT + b * SSq; Cd = A2 + b * SSq;   // A2 = A*(AT)^T = A*A
    }
    tile_1024(Xb, Yb, Cd, ti * 128, tj * 128, Xs, Ys, mir);
}

// ---------------------------------------------------------------------------
// MERGED: gen-2 symmetric pair (576 tile_1024 blocks, dispatched first) +
// fused hop-0 rows (2048 blocks).
// ---------------------------------------------------------------------------
__global__ __launch_bounds__(256) void k_link2_fused0(
    const u16* __restrict__ AAt, const u16* __restrict__ AtA,
    u16* __restrict__ AAt2, u16* __restrict__ AtA2,
    const u16* __restrict__ A, const float* __restrict__ fw,
    const float* __restrict__ fbv, u16* __restrict__ F0)
{
    __shared__ u16 Xs[128 * 64];
    __shared__ u16 Ys[128 * 64];
    const long SSq = (long)SS * SS;
    int bx = blockIdx.x;
    if (bx < 576) {
        int z = bx & 15;
        int tt = bx >> 4, ti = 0;
        while (tt >= 8 - ti) { tt -= 8 - ti; ti++; }
        int tj = ti + tt;
        const u16* Xb = (z < 8 ? AAt : AtA) + (long)(z & 7) * SSq;
        u16* Cd = (z < 8 ? AAt2 : AtA2) + (long)(z & 7) * SSq;
        tile_1024(Xb, Xb, Cd, ti * 128, tj * 128, Xs, Ys, ti != tj);
    } else {
        int lane = threadIdx.x & 63, w = threadIdx.x >> 6;
        float w0 = fw[0], w1 = fw[1], w2 = fw[2], b0 = fbv[0];
        long row = (long)(bx - 576) * 4 + w;
        fused_row(A + row * 1024, AAt + row * 1024, AtA + row * 1024,
                  w0, w1, w2, b0, F0 + row * 1024, lane);
    }
}

// ---------------------------------------------------------------------------
// MERGED: hop-0 GEMM tail (256 split-K blocks, dispatched first) + fused
// hop-1 rows (2048 blocks).
// ---------------------------------------------------------------------------
__global__ __launch_bounds__(256) void k_hop0_fused1(
    const u16* __restrict__ F0, const u16* __restrict__ hopVT,
    float* __restrict__ Pa, float* __restrict__ Pb,
    const u16* __restrict__ A2, const u16* __restrict__ AAt2,
    const u16* __restrict__ AtA2, const float* __restrict__ fw,
    const float* __restrict__ fbv, u16* __restrict__ F1)
{
    __shared__ u16 Fs[128 * 64];
    __shared__ u16 Hs[64 * 64];
    const long SSq = (long)SS * SS;
    int bx = blockIdx.x;
    if (bx < 256) {
        int y = bx >> 6, rest = bx & 63;
        int tmt = rest >> 3, b = rest & 7;
        float* Pd = (y < 2 ? Pa + (long)y * 16 * 65536 : Pb + (long)(y - 2) * 16 * 65536)
                    + (long)b * 65536;                    // hop=0
        hop_tile(F0 + (long)b * SSq, hopVT + (long)b * 65536, y, tmt, Pd, Fs, Hs);
    } else {
        int lane = threadIdx.x & 63, w = threadIdx.x >> 6;
        float w0 = fw[3], w1 = fw[4], w2 = fw[5], b0 = fbv[1];
        long row = (long)(bx - 256) * 4 + w;
        fused_row(A2 + row * 1024, AAt2 + row * 1024, AtA2 + row * 1024,
                  w0, w1, w2, b0, F1 + row * 1024, lane);
    }
}

// hop-1 GEMM standalone, split-K=4: grid 256.
__global__ __launch_bounds__(256) void gemm_hop1(
    const u16* __restrict__ F1, const u16* __restrict__ hopVT,
    float* __restrict__ Pa, float* __restrict__ Pb)
{
    __shared__ u16 Fs[128 * 64];
    __shared__ u16 Hs[64 * 64];
    const long SSq = (long)SS * SS;
    int j = blockIdx.x;
    int y = j >> 6, rest = j & 63;
    int tmt = rest >> 3, b = rest & 7;
    float* Pd = (y < 2 ? Pa + (long)y * 16 * 65536 : Pb + (long)(y - 2) * 16 * 65536)
                + (long)(8 + b) * 65536;                  // hop=1
    hop_tile(F1 + (long)b * SSq, hopVT + (long)(8 + b) * 65536, y, tmt, Pd, Fs, Hs);
}

// ---------------------------------------------------------------------------
// Generic batched NT GEMM (final projection): C[z] = X[z](MxK) * Y[z]^T(NxK)
// ---------------------------------------------------------------------------
__global__ __launch_bounds__(256) void gemm_nt(
    const u16* __restrict__ X, long sx,
    const u16* __restrict__ Y, long sy,
    void* __restrict__ Cv, long sc,
    int M, int N, int K, int cf32)
{
    __shared__ u16 Xs[128 * 64];
    __shared__ u16 Ys[128 * 64];
    const u16* Xb = X + (long)blockIdx.z * sx;
    const u16* Yb = Y + (long)blockIdx.z * sy;
    int tm = blockIdx.x * 128, tn = blockIdx.y * 128;
    int t = threadIdx.x, lane = t & 63, w = t >> 6;
    int wm = (w & 1) << 6, wn = (w >> 1) << 6;
    int fr = lane & 15, q = lane >> 4, m7 = fr & 7;
    int subrow = lane >> 3, cch = (lane & 7) ^ subrow;

    const u16* xg[4]; const u16* yg[4]; u16* xl[4]; u16* yl[4];
    #pragma unroll
    for (int i = 0; i < 4; i++) {
        int r = i * 32 + w * 8 + subrow;
        xg[i] = Xb + (long)(tm + r) * K + cch * 8;
        yg[i] = Yb + (long)(tn + r) * K + cch * 8;
        xl[i] = Xs + (i * 32 + w * 8) * 64;
        yl[i] = Ys + (i * 32 + w * 8) * 64;
    }

    v4f acc[4][4];
    #pragma unroll
    for (int i = 0; i < 4; i++)
        #pragma unroll
        for (int j = 0; j < 4; j++) {
            acc[i][j][0] = 0.f; acc[i][j][1] = 0.f; acc[i][j][2] = 0.f; acc[i][j][3] = 0.f;
        }

    for (int k0 = 0; k0 < K; k0 += 64) {
        __syncthreads();
        #pragma unroll
        for (int i = 0; i < 4; i++) { gload16(xg[i] + k0, xl[i]); gload16(yg[i] + k0, yl[i]); }
        __syncthreads();
        v8s af[2][4], bfr[2][4];
        #pragma unroll
        for (int h = 0; h < 2; h++) {
            int ca = (((h << 2) + q) ^ m7) << 3;
            #pragma unroll
            for (int s = 0; s < 4; s++) {
                af[h][s]  = *(const v8s*)(Xs + (wm + s * 16 + fr) * 64 + ca);
                bfr[h][s] = *(const v8s*)(Ys + (wn + s * 16 + fr) * 64 + ca);
            }
        }
        #pragma unroll
        for (int h = 0; h < 2; h++)
            #pragma unroll
            for (int i = 0; i < 4; i++)
                #pragma unroll
                for (int j = 0; j < 4; j++)
                    acc[i][j] = __builtin_amdgcn_mfma_f32_16x16x32_bf16(af[h][i], bfr[h][j], acc[i][j], 0, 0, 0);
    }
    long cb = (long)blockIdx.z * sc;
    #pragma unroll
    for (int i = 0; i < 4; i++) {
        int rowb = tm + wm + i * 16 + q * 4;
        #pragma unroll
        for (int j = 0; j < 4; j++) {
            int col = tn + wn + j * 16 + fr;
            #pragma unroll
            for (int r = 0; r < 4; r++) {
                long o = cb + (long)(rowb + r) * N + col;
                if (cf32) ((float*)Cv)[o] = acc[i][j][r];
                else      ((u16*)Cv)[o] = f2bf(acc[i][j][r]);
            }
        }
    }
}

// ---------------------------------------------------------------------------
// Projection GEMM with FUSED RoPE + gate-softmax epilogue (R3-verified form:
// 128 blocks x 256 thr, reads pre-packed xb via async gload16).
// Grid (64,2): by=0 -> cols 0..127 = Q|K, by=1 -> cols 128..255 = V | gate.
// ---------------------------------------------------------------------------
__global__ __launch_bounds__(256) void k_proj_rope(
    const u16* __restrict__ xb, const u16* __restrict__ wpack,
    const float* __restrict__ gateb, const float2* __restrict__ ropetab,
    u16* __restrict__ Qb, u16* __restrict__ Kb, u16* __restrict__ Vb,
    float* __restrict__ gate)
{
    __shared__ u16 Xs[128 * 64];
    __shared__ u16 Ys[128 * 64];
    int tm = blockIdx.x * 128, tn = blockIdx.y * 128;
    int t = threadIdx.x, lane = t & 63, w = t >> 6;
    int wm = (w & 1) << 6, wn = (w >> 1) << 6;
    int fr = lane & 15, q = lane >> 4, m7 = fr & 7;
    int subrow = lane >> 3, cch = (lane & 7) ^ subrow;

    const u16* xg[4]; const u16* yg[4]; u16* xl[4]; u16* yl[4];
    #pragma unroll
    for (int i = 0; i < 4; i++) {
        int r = i * 32 + w * 8 + subrow;
        xg[i] = xb + (long)(tm + r) * 512 + cch * 8;
        yg[i] = wpack + (long)(tn + r) * 512 + cch * 8;
        xl[i] = Xs + (i * 32 + w * 8) * 64;
        yl[i] = Ys + (i * 32 + w * 8) * 64;
    }

    v4f acc[4][4];
    #pragma unroll
    for (int i = 0; i < 4; i++)
        #pragma unroll
        for (int j = 0; j < 4; j++) {
            acc[i][j][0] = 0.f; acc[i][j][1] = 0.f; acc[i][j][2] = 0.f; acc[i][j][3] = 0.f;
        }

    for (int k0 = 0; k0 < 512; k0 += 64) {
        __syncthreads();
        #pragma unroll
        for (int i = 0; i < 4; i++) { gload16(xg[i] + k0, xl[i]); gload16(yg[i] + k0, yl[i]); }
        __syncthreads();
        v8s af[2][4], bfr[2][4];
        #pragma unroll
        for (int h = 0; h < 2; h++) {
            int ca = (((h << 2) + q) ^ m7) << 3;
            #pragma unroll
            for (int s = 0; s < 4; s++) {
                af[h][s]  = *(const v8s*)(Xs + (wm + s * 16 + fr) * 64 + ca);
                bfr[h][s] = *(const v8s*)(Ys + (wn + s * 16 + fr) * 64 + ca);
            }
        }
        #pragma unroll
        for (int h = 0; h < 2; h++)
            #pragma unroll
            for (int i = 0; i < 4; i++)
                #pragma unroll
                for (int j = 0; j < 4; j++)
                    acc[i][j] = __builtin_amdgcn_mfma_f32_16x16x32_bf16(af[h][i], bfr[h][j], acc[i][j], 0, 0, 0);
    }

    if (blockIdx.y == 0) {
        u16* dst = wn ? Kb : Qb;
        #pragma unroll
        for (int i = 0; i < 4; i++) {
            #pragma unroll
            for (int r = 0; r < 4; r++) {
                int row = tm + wm + i * 16 + q * 4 + r;
                int spos = row & (SS - 1);
                float2 t0 = ropetab[spos * 32 + fr];        // f = fr   (j even)
                float2 t1 = ropetab[spos * 32 + 16 + fr];   // f = fr+16 (j odd)
                #pragma unroll
                for (int j = 0; j < 4; j++) {
                    float v = acc[i][j][r], p = acc[i][j ^ 2][r];
                    float cs = (j & 1) ? t1.x : t0.x;
                    float sn = (j & 1) ? t1.y : t0.y;
                    float o = (j & 2) ? (v * cs + p * sn) : (v * cs - p * sn);
                    dst[(long)row * 64 + j * 16 + fr] = f2bf(o);
                }
            }
        }
    } else if (wn == 0) {
        #pragma unroll
        for (int i = 0; i < 4; i++)
            #pragma unroll
            for (int j = 0; j < 4; j++)
                #pragma unroll
                for (int r = 0; r < 4; r++) {
                    int row = tm + wm + i * 16 + q * 4 + r;
                    Vb[(long)row * 64 + j * 16 + fr] = f2bf(acc[i][j][r]);
                }
    } else {
        float gb = gateb[fr & 1];
        #pragma unroll
        for (int i = 0; i < 4; i++)
            #pragma unroll
            for (int r = 0; r < 4; r++) {
                int row = tm + wm + i * 16 + q * 4 + r;
                float g = acc[i][0][r] + gb;
                float go = __shfl_xor(g, 1);
                float m = fmaxf(g, go);
                float e = __expf(g - m), eo = __expf(go - m);
                if (fr < 2) gate[(long)row * 2 + fr] = e / (e + eo);
            }
    }
}

// pack x + weights to bf16 (merged) + rope cos/sin table
__global__ __launch_bounds__(256) void k_pack(
    const float* __restrict__ x, const float* __restrict__ Wq,
    const float* __restrict__ Wk, const float* __restrict__ Wv,
    const float* __restrict__ gW, const float* __restrict__ hopW,
    const float* __restrict__ outW, u16* __restrict__ xb,
    u16* __restrict__ wpack, u16* __restrict__ hopWb, u16* __restrict__ outWb,
    float2* __restrict__ ropetab)
{
    int bx = blockIdx.x;
    if (bx < 4096) {
        long i = (long)bx * 256 + threadIdx.x;
        float4 v = ((const float4*)x)[i];
        ushort4 o;
        o.x = f2bf(v.x); o.y = f2bf(v.y); o.z = f2bf(v.z); o.w = f2bf(v.w);
        ((ushort4*)xb)[i] = o;
    } else if (bx < 4768) {
        int idx = (bx - 4096) * 256 + threadIdx.x;
        if (idx < 131072) {
            int r = idx >> 9, c = idx & 511;
            float v = 0.f;
            if (r < 64)       v = Wq[r * 512 + c];
            else if (r < 128) v = Wk[(r - 64) * 512 + c];
            else if (r < 192) v = Wv[(r - 128) * 512 + c];
            else if (r < 194) v = gW[(r - 192) * 512 + c];
            wpack[idx] = f2bf(v);
        } else if (idx < 131072 + 8192) {
            int i = idx - 131072;
            hopWb[i] = f2bf(hopW[i]);
        } else if (idx < 131072 + 8192 + 32768) {
            int i = idx - 131072 - 8192;
            outWb[i] = f2bf(outW[i]);
        }
    } else {
        int idx = (bx - 4768) * 256 + threadIdx.x;   // 0..32767
        int spos = idx >> 5, f = idx & 31;
        float ang = (float)spos * exp2f(-(float)f * (13.287712379549449f / 32.0f));
        float sn, cs;
        sincosf(ang, &sn, &cs);
        ropetab[idx] = make_float2(cs, sn);
    }
}

// sum split-K=4 partials, gate-combine -> comb bf16 [8192][64].
// Vectorized: 4 elems/thread (same row), 8x float4 reads + ushort4 store.
__global__ __launch_bounds__(256) void k_combine(
    const float* __restrict__ Pa, const float* __restrict__ Pb,
    const float* __restrict__ gate, u16* __restrict__ comb)
{
    long idx = ((long)blockIdx.x * 256 + threadIdx.x) * 4;   // 8192*64 total
    long srow = idx >> 6;
    int b = (int)(srow >> 10);
    long o = (long)(srow & 1023) * 64 + (idx & 63);
    float4 a0 = *(const float4*)(Pa + (long)b * 65536 + o);
    float4 a1 = *(const float4*)(Pa + (long)(16 + b) * 65536 + o);
    float4 b0 = *(const float4*)(Pb + (long)b * 65536 + o);
    float4 b1 = *(const float4*)(Pb + (long)(16 + b) * 65536 + o);
    float4 c0 = *(const float4*)(Pa + (long)(8 + b) * 65536 + o);
    float4 c1 = *(const float4*)(Pa + (long)(24 + b) * 65536 + o);
    float4 d0 = *(const float4*)(Pb + (long)(8 + b) * 65536 + o);
    float4 d1 = *(const float4*)(Pb + (long)(24 + b) * 65536 + o);
    float g0 = gate[srow * 2], g1 = gate[srow * 2 + 1];
    ushort4 ov;
    ov.x = f2bf((a0.x + a1.x + b0.x + b1.x) * g0 + (c0.x + c1.x + d0.x + d1.x) * g1);
    ov.y = f2bf((a0.y + a1.y + b0.y + b1.y) * g0 + (c0.y + c1.y + d0.y + d1.y) * g1);
    ov.z = f2bf((a0.z + a1.z + b0.z + b1.z) * g0 + (c0.z + c1.z + d0.z + d1.z) * g1);
    ov.w = f2bf((a0.w + a1.w + b0.w + b1.w) * g0 + (c0.w + c1.w + d0.w + d1.w) * g1);
    *(ushort4*)(comb + idx) = ov;
}

// ---------------------------------------------------------------------------
extern "C" void kernel_launch(void* const* d_in, const int* in_sizes, int n_in,
                              void* d_out, int out_size, void* d_ws, size_t ws_size,
                              hipStream_t stream) {
    const float* x    = (const float*)d_in[0];
    const float* Wq   = (const float*)d_in[1];
    const float* Wk   = (const float*)d_in[2];
    const float* Wv   = (const float*)d_in[3];
    const float* btab = (const float*)d_in[4];
    const float* fw   = (const float*)d_in[5];
    const float* fbv  = (const float*)d_in[6];
    const float* hopW = (const float*)d_in[7];
    const float* gW   = (const float*)d_in[8];
    const float* gb   = (const float*)d_in[9];
    const float* outW = (const float*)d_in[10];
    const float* temp = (const float*)d_in[11];
    float* out = (float*)d_out;

    char* wsb = (char*)d_ws;
    size_t off = 0;
    auto take = [&](size_t n) { char* p = wsb + off; off += (n + 255) & ~(size_t)255; return p; };
    u16* Qb      = (u16*)take(8192L * 64 * 2);
    u16* Kb      = (u16*)take(8192L * 64 * 2);
    u16* Vb      = (u16*)take(8192L * 64 * 2);
    float* gate  = (float*)take(8192L * 2 * 4);
    u16* wpack   = (u16*)take(256L * 512 * 2);
    u16* hopWb   = (u16*)take(2L * 64 * 64 * 2);
    u16* outWb   = (u16*)take(512L * 64 * 2);
    float2* ropetab = (float2*)take(1024L * 32 * 8);
    u16* hopVT   = (u16*)take(2L * 8 * 64 * 1024 * 2);
    float* Pa    = (float*)take(2L * 16 * 65536 * 4);     // split-K partials y=0,1
    u16* comb    = (u16*)take(8192L * 64 * 2);
    char* fregion = take(8L * 1024 * 1024 * 4);       // 32 MB region for F0/F1
    u16* F0      = (u16*)fregion;
    u16* F1      = (u16*)fregion + 8L * 1024 * 1024;  // second 16 MB of region
    u16* A       = (u16*)take(8L * 1024 * 1024 * 2);
    u16* xb      = (u16*)A;                           // alias: xb dead before A
    u16* AT      = (u16*)take(8L * 1024 * 1024 * 2);
    float* Pb    = (float*)AT;                        // alias: AT dead after link1
    u16* AAt     = (u16*)take(8L * 1024 * 1024 * 2);
    u16* AtA     = (u16*)take(8L * 1024 * 1024 * 2);
    u16* A2      = (u16*)take(8L * 1024 * 1024 * 2);
    u16* AAt2    = (u16*)take(8L * 1024 * 1024 * 2);
    u16* AtA2    = (u16*)take(8L * 1024 * 1024 * 2);
    (void)ws_size; (void)in_sizes; (void)n_in; (void)out_size;

    // 1. pack inputs + rope table
    k_pack<<<4896, 256, 0, stream>>>(x, Wq, Wk, Wv, gW, hopW, outW, xb, wpack,
                                     hopWb, outWb, ropetab);
    // 2. projection GEMM with fused rope + gate softmax
    k_proj_rope<<<dim3(64, 2, 1), 256, 0, stream>>>(xb, wpack, gb, ropetab,
                                                    Qb, Kb, Vb, gate);
    // 3. fused QK^T + bias + softmax -> A, AT (no fp32 scores round-trip)
    k_qksm<<<512, 256, 0, stream>>>(Qb, Kb, btab, temp, A, AT);
    // 4. generation-1: AAt, AtA (reg-mirrored) + A2 + hopV rider -> hopVT
    gemm_link1<<<1152, 256, 0, stream>>>(A, AT, AAt, AtA, A2, Vb, hopWb, hopVT);
    // 5. gen-2 sym pair (576 GEMM blocks first) + fused hop-0 rows (2048)
    k_link2_fused0<<<2624, 256, 0, stream>>>(AAt, AtA, AAt2, AtA2, A, fw, fbv, F0);
    // 6. hop-0 GEMM tail (256 first) + fused hop-1 rows (2048)
    k_hop0_fused1<<<2304, 256, 0, stream>>>(F0, hopVT, Pa, Pb, A2, AAt2, AtA2,
                                            fw, fbv, F1);
    // 7. hop-1 GEMM
    gemm_hop1<<<256, 256, 0, stream>>>(F1, hopVT, Pa, Pb);
    // 8. combine (vectorized x4) + output projection
    k_combine<<<512, 256, 0, stream>>>(Pa, Pb, gate, comb);
    gemm_nt<<<dim3(64, 4, 1), 256, 0, stream>>>(comb, 0, outWb, 0, out, 0, 8192, 512, 64, 1);
}

// Round 6
// 276.307 us; speedup vs baseline: 1.0399x; 1.0035x over previous
//
#include <hip/hip_runtime.h>
#include <hip/hip_bf16.h>

// Problem constants
#define BB 8
#define SS 1024
#define HH 512
#define DD 64

typedef unsigned short u16;
typedef short v8s __attribute__((ext_vector_type(8)));   // 8 x bf16 (bit pattern)
typedef float v4f __attribute__((ext_vector_type(4)));

__device__ __forceinline__ float bf2f(u16 u) {
    union { unsigned int i; float f; } v; v.i = ((unsigned int)u) << 16; return v.f;
}
__device__ __forceinline__ u16 f2bf(float f) {
    union { float f; unsigned int i; } v; v.f = f;
    unsigned int u = v.i;
    unsigned int r = u + 0x7fffu + ((u >> 16) & 1u);   // RNE
    return (u16)(r >> 16);
}

// async 16B global->LDS DMA: lane L's data lands at ldsbase + L*16
__device__ __forceinline__ void gload16(const u16* g, u16* l) {
    __builtin_amdgcn_global_load_lds(
        (const __attribute__((address_space(1))) void*)g,
        (__attribute__((address_space(3))) void*)l,
        16, 0, 0);
}

// ---------------------------------------------------------------------------
// Shared GEMM geometry (BK=64): LDS rows of 64 bf16 = 8 chunks of 16B.
// Physical chunk p of row r holds logical chunk p ^ (r&7) (conflict-free b128).
// Staging: thread t=64w+lane, instr i: row = i*32 + w*8 + (lane>>3),
//          phys chunk = lane&7, global col chunk = (lane&7) ^ (lane>>3).
//
// tile_1024: 128x128 tile x K=1024 NT product, bf16 out. mirror!=0 (symmetric
// product, off-diagonal tile): ALSO writes C[tn..][tm..] = tile^T directly
// from registers — C-layout gives each lane 4 consecutive rows of one column,
// i.e. 4 consecutive u16 of the transposed tile -> one packed 8B store.
// ---------------------------------------------------------------------------
__device__ __forceinline__ void tile_1024(
    const u16* __restrict__ Xb, const u16* __restrict__ Yb,
    u16* __restrict__ Cd, int tm, int tn, u16* Xs, u16* Ys, int mirror)
{
    int t = threadIdx.x, lane = t & 63, w = t >> 6;
    int wm = (w & 1) << 6, wn = (w >> 1) << 6;
    int fr = lane & 15, q = lane >> 4, m7 = fr & 7;
    int subrow = lane >> 3, cch = (lane & 7) ^ subrow;

    const u16* xg[4]; const u16* yg[4]; u16* xl[4]; u16* yl[4];
    #pragma unroll
    for (int i = 0; i < 4; i++) {
        int r = i * 32 + w * 8 + subrow;
        xg[i] = Xb + (long)(tm + r) * 1024 + cch * 8;
        yg[i] = Yb + (long)(tn + r) * 1024 + cch * 8;
        xl[i] = Xs + (i * 32 + w * 8) * 64;
        yl[i] = Ys + (i * 32 + w * 8) * 64;
    }

    v4f acc[4][4];
    #pragma unroll
    for (int i = 0; i < 4; i++)
        #pragma unroll
        for (int j = 0; j < 4; j++) {
            acc[i][j][0] = 0.f; acc[i][j][1] = 0.f; acc[i][j][2] = 0.f; acc[i][j][3] = 0.f;
        }

    for (int k0 = 0; k0 < 1024; k0 += 64) {
        __syncthreads();
        #pragma unroll
        for (int i = 0; i < 4; i++) { gload16(xg[i] + k0, xl[i]); gload16(yg[i] + k0, yl[i]); }
        __syncthreads();
        v8s af[2][4], bfr[2][4];
        #pragma unroll
        for (int h = 0; h < 2; h++) {
            int ca = (((h << 2) + q) ^ m7) << 3;
            #pragma unroll
            for (int s = 0; s < 4; s++) {
                af[h][s]  = *(const v8s*)(Xs + (wm + s * 16 + fr) * 64 + ca);
                bfr[h][s] = *(const v8s*)(Ys + (wn + s * 16 + fr) * 64 + ca);
            }
        }
        #pragma unroll
        for (int h = 0; h < 2; h++)
            #pragma unroll
            for (int i = 0; i < 4; i++)
                #pragma unroll
                for (int j = 0; j < 4; j++)
                    acc[i][j] = __builtin_amdgcn_mfma_f32_16x16x32_bf16(af[h][i], bfr[h][j], acc[i][j], 0, 0, 0);
    }
    #pragma unroll
    for (int i = 0; i < 4; i++) {
        int rowb = tm + wm + i * 16 + q * 4;
        #pragma unroll
        for (int j = 0; j < 4; j++) {
            int col = tn + wn + j * 16 + fr;
            ushort4 pv;
            pv.x = f2bf(acc[i][j][0]); pv.y = f2bf(acc[i][j][1]);
            pv.z = f2bf(acc[i][j][2]); pv.w = f2bf(acc[i][j][3]);
            #pragma unroll
            for (int r = 0; r < 4; r++)
                Cd[(long)(rowb + r) * 1024 + col] = ((u16*)&pv)[r];
            if (mirror)   // transposed tile: 4 consecutive u16 at row=col
                *(ushort4*)(Cd + (long)col * 1024 + rowb) = pv;
        }
    }
}

// ---------------------------------------------------------------------------
// hopV projection tile (K=64, 128 rows of V x 128 rows of hopWb), writing the
// TRANSPOSED result directly to hopVT[(hop*8+z)][e][s]: each lane's acc[i][j]
// holds 4 consecutive s-rows of one e-column -> one packed 8B store.
// ---------------------------------------------------------------------------
__device__ __forceinline__ void hopv_tile(
    const u16* __restrict__ Vrows, const u16* __restrict__ Hw,
    u16* __restrict__ hopVT, int tm, u16* Xs, u16* Ys)
{
    int t = threadIdx.x, lane = t & 63, w = t >> 6;
    int wm = (w & 1) << 6, wn = (w >> 1) << 6;
    int fr = lane & 15, q = lane >> 4, m7 = fr & 7;
    int subrow = lane >> 3, cch = (lane & 7) ^ subrow;

    #pragma unroll
    for (int i = 0; i < 4; i++) {
        int r = i * 32 + w * 8 + subrow;
        gload16(Vrows + (long)(tm + r) * 64 + cch * 8, Xs + (i * 32 + w * 8) * 64);
        gload16(Hw + (long)r * 64 + cch * 8, Ys + (i * 32 + w * 8) * 64);
    }
    __syncthreads();

    v4f acc[4][4];
    #pragma unroll
    for (int i = 0; i < 4; i++)
        #pragma unroll
        for (int j = 0; j < 4; j++) {
            acc[i][j][0] = 0.f; acc[i][j][1] = 0.f; acc[i][j][2] = 0.f; acc[i][j][3] = 0.f;
        }
    v8s af[2][4], bfr[2][4];
    #pragma unroll
    for (int h = 0; h < 2; h++) {
        int ca = (((h << 2) + q) ^ m7) << 3;
        #pragma unroll
        for (int s = 0; s < 4; s++) {
            af[h][s]  = *(const v8s*)(Xs + (wm + s * 16 + fr) * 64 + ca);
            bfr[h][s] = *(const v8s*)(Ys + (wn + s * 16 + fr) * 64 + ca);
        }
    }
    #pragma unroll
    for (int h = 0; h < 2; h++)
        #pragma unroll
        for (int i = 0; i < 4; i++)
            #pragma unroll
            for (int j = 0; j < 4; j++)
                acc[i][j] = __builtin_amdgcn_mfma_f32_16x16x32_bf16(af[h][i], bfr[h][j], acc[i][j], 0, 0, 0);

    int z = tm >> 10, sb = tm & 1023;
    #pragma unroll
    for (int i = 0; i < 4; i++) {
        int rowb = wm + i * 16 + q * 4;
        #pragma unroll
        for (int j = 0; j < 4; j++) {
            int colY = wn + j * 16 + fr;
            int hop = colY >> 6, e = colY & 63;
            ushort4 pv;
            pv.x = f2bf(acc[i][j][0]); pv.y = f2bf(acc[i][j][1]);
            pv.z = f2bf(acc[i][j][2]); pv.w = f2bf(acc[i][j][3]);
            *(ushort4*)(hopVT + (long)(hop * 8 + z) * 65536 + (long)e * 1024 + sb + rowb) = pv;
        }
    }
}

// 128x64 F@H^T tile over K-range [y*256,(y+1)*256). Fs:128x64, Hs:64x64 LDS.
__device__ __forceinline__ void hop_tile(
    const u16* __restrict__ Fb, const u16* __restrict__ Hb,
    int y, int tmt, float* __restrict__ Pd, u16* Fs, u16* Hs)
{
    int tm = tmt * 128, kb = y * 256;
    int t = threadIdx.x, lane = t & 63, w = t >> 6;
    int fr = lane & 15, q = lane >> 4, m7 = fr & 7;
    int subrow = lane >> 3, cch = (lane & 7) ^ subrow;

    const u16* fg[4]; u16* fl[4]; const u16* hg[2]; u16* hl[2];
    #pragma unroll
    for (int i = 0; i < 4; i++) {
        int r = i * 32 + w * 8 + subrow;
        fg[i] = Fb + (long)(tm + r) * 1024 + cch * 8;
        fl[i] = Fs + (i * 32 + w * 8) * 64;
    }
    #pragma unroll
    for (int i = 0; i < 2; i++) {
        int r = i * 32 + w * 8 + subrow;
        hg[i] = Hb + (long)r * 1024 + cch * 8;
        hl[i] = Hs + (i * 32 + w * 8) * 64;
    }

    v4f acc[2][4];
    #pragma unroll
    for (int i = 0; i < 2; i++)
        #pragma unroll
        for (int j = 0; j < 4; j++) {
            acc[i][j][0] = 0.f; acc[i][j][1] = 0.f; acc[i][j][2] = 0.f; acc[i][j][3] = 0.f;
        }

    for (int k0 = kb; k0 < kb + 256; k0 += 64) {
        __syncthreads();
        #pragma unroll
        for (int i = 0; i < 4; i++) gload16(fg[i] + k0, fl[i]);
        #pragma unroll
        for (int i = 0; i < 2; i++) gload16(hg[i] + k0, hl[i]);
        __syncthreads();
        v8s af[2][2], bfr[2][4];
        #pragma unroll
        for (int h = 0; h < 2; h++) {
            int ca = (((h << 2) + q) ^ m7) << 3;
            #pragma unroll
            for (int s = 0; s < 2; s++)
                af[h][s] = *(const v8s*)(Fs + (w * 32 + s * 16 + fr) * 64 + ca);
            #pragma unroll
            for (int s = 0; s < 4; s++)
                bfr[h][s] = *(const v8s*)(Hs + (s * 16 + fr) * 64 + ca);
        }
        #pragma unroll
        for (int h = 0; h < 2; h++)
            #pragma unroll
            for (int i = 0; i < 2; i++)
                #pragma unroll
                for (int j = 0; j < 4; j++)
                    acc[i][j] = __builtin_amdgcn_mfma_f32_16x16x32_bf16(af[h][i], bfr[h][j], acc[i][j], 0, 0, 0);
    }
    #pragma unroll
    for (int i = 0; i < 2; i++) {
        int rowb = tm + w * 32 + i * 16 + q * 4;
        #pragma unroll
        for (int j = 0; j < 4; j++) {
            int col = j * 16 + fr;
            #pragma unroll
            for (int r = 0; r < 4; r++)
                Pd[(long)(rowb + r) * 64 + col] = acc[i][j][r];
        }
    }
}

// fused prob_log/sigmoid/row-norm for one row (wave-collective, 64 lanes).
__device__ __forceinline__ void fused_row(
    const u16* __restrict__ r1, const u16* __restrict__ r2, const u16* __restrict__ r3,
    float w0, float w1, float w2, float b0, u16* __restrict__ Frow, int lane)
{
    int base = lane << 4;
    union U { uint4 v; u16 s[8]; };
    U a[2], b[2], c[2];
    a[0].v = *(const uint4*)(r1 + base); a[1].v = *(const uint4*)(r1 + base + 8);
    b[0].v = *(const uint4*)(r2 + base); b[1].v = *(const uint4*)(r2 + base + 8);
    c[0].v = *(const uint4*)(r3 + base); c[1].v = *(const uint4*)(r3 + base + 8);
    float m1[16], m2[16], m3[16];
    float s1 = 0.f, s2 = 0.f, s3 = 0.f;
    #pragma unroll
    for (int h = 0; h < 2; h++)
        #pragma unroll
        for (int e = 0; e < 8; e++) {
            int k = h * 8 + e;
            m1[k] = bf2f(a[h].s[e]); m2[k] = bf2f(b[h].s[e]); m3[k] = bf2f(c[h].s[e]);
            s1 += m1[k]; s2 += m2[k]; s3 += m3[k];
        }
    #pragma unroll
    for (int o = 1; o < 64; o <<= 1) {
        s1 += __shfl_xor(s1, o); s2 += __shfl_xor(s2, o); s3 += __shfl_xor(s3, o);
    }
    float i1 = 1.f / (s1 + 1e-6f), i2 = 1.f / (s2 + 1e-6f), i3 = 1.f / (s3 + 1e-6f);
    float sig[16];
    float ssum = 0.f;
    #pragma unroll
    for (int k = 0; k < 16; k++) {
        float p1 = fminf(fmaxf(m1[k] * i1, 1e-6f), 1.0f - 1e-6f);
        float p2 = fminf(fmaxf(m2[k] * i2, 1e-6f), 1.0f - 1e-6f);
        float p3 = fminf(fmaxf(m3[k] * i3, 1e-6f), 1.0f - 1e-6f);
        float l1 = __logf(p1 / (1.0f - p1 + 1e-6f));
        float l2 = __logf(p2 / (1.0f - p2 + 1e-6f));
        float l3 = __logf(p3 / (1.0f - p3 + 1e-6f));
        float lg = b0 + w0 * l1 + w1 * l2 + w2 * l3;
        float sg = 1.0f / (1.0f + __expf(-lg));
        sig[k] = sg; ssum += sg;
    }
    #pragma unroll
    for (int o = 1; o < 64; o <<= 1) ssum += __shfl_xor(ssum, o);
    float inv = 1.0f / (ssum + 1e-6f);
    U o0, o1;
    #pragma unroll
    for (int e = 0; e < 8; e++) { o0.s[e] = f2bf(sig[e] * inv); o1.s[e] = f2bf(sig[8 + e] * inv); }
    *(uint4*)(Frow + base) = o0.v;
    *(uint4*)(Frow + base + 8) = o1.v;
}

// ---------------------------------------------------------------------------
// Fused QK^T + bias + temperature + softmax -> A and AT (no-max softmax; see
// R3 notes). 512 blocks x 256 thr.
// ---------------------------------------------------------------------------
__global__ __launch_bounds__(256) void k_qksm(
    const u16* __restrict__ Qb, const u16* __restrict__ Kb,
    const float* __restrict__ btab, const float* __restrict__ temp,
    u16* __restrict__ A, u16* __restrict__ AT)
{
    __shared__ __align__(16) float smf[3969];
    __shared__ float lred[4][16];
    int t = threadIdx.x, lane = t & 63, w = t >> 6;
    int fr = lane & 15, q4 = lane >> 4;
    int bx = blockIdx.x;
    int z = bx >> 6;
    int rb = (bx & 63) << 4;                  // q-row base within batch
    for (int i = t; i < 3969; i += 256) smf[i] = btab[i];
    __syncthreads();
    float invt = 1.0f / fmaxf(temp[0], 0.1f);
    const long SD = (long)SS * DD;
    const long SSq = (long)SS * SS;
    const u16* qrow = Qb + (long)z * SD + (long)(rb + fr) * 64 + q4 * 8;
    v8s aq0 = *(const v8s*)(qrow);
    v8s aq1 = *(const v8s*)(qrow + 32);
    int ih[4], iw[4];
    #pragma unroll
    for (int r = 0; r < 4; r++) {
        int ii = rb + q4 * 4 + r;
        ih[r] = ii >> 5; iw[r] = ii & 31;
    }
    const u16* kb0 = Kb + (long)z * SD + q4 * 8;
    int c0 = w << 8;
    float ef[16][4];
    float l0 = 0.f, l1 = 0.f, l2 = 0.f, l3 = 0.f;
    #pragma unroll
    for (int f = 0; f < 16; f++) {
        int colK = c0 + f * 16 + fr;
        const u16* krow = kb0 + (long)colK * 64;
        v8s bk0 = *(const v8s*)(krow);
        v8s bk1 = *(const v8s*)(krow + 32);
        v4f acc = {0.f, 0.f, 0.f, 0.f};
        acc = __builtin_amdgcn_mfma_f32_16x16x32_bf16(aq0, bk0, acc, 0, 0, 0);
        acc = __builtin_amdgcn_mfma_f32_16x16x32_bf16(aq1, bk1, acc, 0, 0, 0);
        int jh = colK >> 5, jw = colK & 31;
        #pragma unroll
        for (int r = 0; r < 4; r++) {
            float pb = smf[(ih[r] - jh + 31) * 63 + (iw[r] - jw + 31)];
            float s = (acc[r] * 0.125f + pb) * invt;
            float e = __expf(s);
            ef[f][r] = e;
            if (r == 0) l0 += e; else if (r == 1) l1 += e;
            else if (r == 2) l2 += e; else l3 += e;
        }
    }
    #pragma unroll
    for (int o = 1; o < 16; o <<= 1) {
        l0 += __shfl_xor(l0, o); l1 += __shfl_xor(l1, o);
        l2 += __shfl_xor(l2, o); l3 += __shfl_xor(l3, o);
    }
    if (fr == 0) {
        lred[w][q4 * 4 + 0] = l0; lred[w][q4 * 4 + 1] = l1;
        lred[w][q4 * 4 + 2] = l2; lred[w][q4 * 4 + 3] = l3;
    }
    __syncthreads();
    float invl[4];
    #pragma unroll
    for (int r = 0; r < 4; r++) {
        int idx = q4 * 4 + r;
        invl[r] = 1.0f / (lred[0][idx] + lred[1][idx] + lred[2][idx] + lred[3][idx]);
    }
    u16* Ab = A + (long)z * SSq;
    u16* ATb = AT + (long)z * SSq;
    #pragma unroll
    for (int f = 0; f < 16; f++) {
        int colK = c0 + f * 16 + fr;
        ushort4 pv;
        u16* pp = (u16*)&pv;
        #pragma unroll
        for (int r = 0; r < 4; r++) {
            u16 bv = f2bf(ef[f][r] * invl[r]);
            pp[r] = bv;
            Ab[(long)(rb + q4 * 4 + r) * 1024 + colK] = bv;
        }
        *(ushort4*)(ATb + (long)colK * 1024 + rb + q4 * 4) = pv;
    }
}

// ---------------------------------------------------------------------------
// Generation-1: AAt (upper 36, reg-mirrored), AtA (same), A2 = A*A (full 64).
// blocks 0..1087: 8 batches x 136 jobs, batch = blockIdx.x & 7 (XCD locality).
// blocks 1088..1151: hopV projection rider (64 blocks) -> hopVT direct.
// ---------------------------------------------------------------------------
__global__ __launch_bounds__(256) void gemm_link1(
    const u16* __restrict__ A, const u16* __restrict__ AT,
    u16* __restrict__ AAt, u16* __restrict__ AtA, u16* __restrict__ A2,
    const u16* __restrict__ Vb, const u16* __restrict__ hopWb,
    u16* __restrict__ hopVT)
{
    __shared__ u16 Xs[128 * 64];
    __shared__ u16 Ys[128 * 64];
    const long SSq = (long)SS * SS;
    if (blockIdx.x >= 1088) {
        hopv_tile(Vb, hopWb, hopVT, (blockIdx.x - 1088) * 128, Xs, Ys);
        return;
    }
    int b = blockIdx.x & 7;
    int job = blockIdx.x >> 3;
    const u16* Xb; const u16* Yb; u16* Cd;
    int ti, tj, mir;
    if (job < 72) {
        int tt = job < 36 ? job : job - 36;
        ti = 0;
        while (tt >= 8 - ti) { tt -= 8 - ti; ti++; }
        tj = ti + tt;
        mir = (ti != tj);
        if (job < 36) { Xb = A  + b * SSq; Yb = Xb; Cd = AAt + b * SSq; }
        else          { Xb = AT + b * SSq; Yb = Xb; Cd = AtA + b * SSq; }
    } else {
        int jj = job - 72;
        ti = jj >> 3; tj = jj & 7; mir = 0;
        Xb = A + b * SSq; Yb = AT + b * SSq; Cd = A2 + b * SSq;   // A2 = A*(AT)^T = A*A
    }
    tile_1024(Xb, Yb, Cd, ti * 128, tj * 128, Xs, Ys, mir);
}

// ---------------------------------------------------------------------------
// MERGED: gen-2 symmetric pair (576 tile_1024 blocks, dispatched first) +
// fused hop-0 rows (2048 blocks).
// ---------------------------------------------------------------------------
__global__ __launch_bounds__(256) void k_link2_fused0(
    const u16* __restrict__ AAt, const u16* __restrict__ AtA,
    u16* __restrict__ AAt2, u16* __restrict__ AtA2,
    const u16* __restrict__ A, const float* __restrict__ fw,
    const float* __restrict__ fbv, u16* __restrict__ F0)
{
    __shared__ u16 Xs[128 * 64];
    __shared__ u16 Ys[128 * 64];
    const long SSq = (long)SS * SS;
    int bx = blockIdx.x;
    if (bx < 576) {
        int z = bx & 15;
        int tt = bx >> 4, ti = 0;
        while (tt >= 8 - ti) { tt -= 8 - ti; ti++; }
        int tj = ti + tt;
        const u16* Xb = (z < 8 ? AAt : AtA) + (long)(z & 7) * SSq;
        u16* Cd = (z < 8 ? AAt2 : AtA2) + (long)(z & 7) * SSq;
        tile_1024(Xb, Xb, Cd, ti * 128, tj * 128, Xs, Ys, ti != tj);
    } else {
        int lane = threadIdx.x & 63, w = threadIdx.x >> 6;
        float w0 = fw[0], w1 = fw[1], w2 = fw[2], b0 = fbv[0];
        long row = (long)(bx - 576) * 4 + w;
        fused_row(A + row * 1024, AAt + row * 1024, AtA + row * 1024,
                  w0, w1, w2, b0, F0 + row * 1024, lane);
    }
}

// ---------------------------------------------------------------------------
// MERGED: hop-0 GEMM tail (256 split-K blocks, dispatched first) + fused
// hop-1 rows (2048 blocks).
// ---------------------------------------------------------------------------
__global__ __launch_bounds__(256) void k_hop0_fused1(
    const u16* __restrict__ F0, const u16* __restrict__ hopVT,
    float* __restrict__ Pa, float* __restrict__ Pb,
    const u16* __restrict__ A2, const u16* __restrict__ AAt2,
    const u16* __restrict__ AtA2, const float* __restrict__ fw,
    const float* __restrict__ fbv, u16* __restrict__ F1)
{
    __shared__ u16 Fs[128 * 64];
    __shared__ u16 Hs[64 * 64];
    const long SSq = (long)SS * SS;
    int bx = blockIdx.x;
    if (bx < 256) {
        int y = bx >> 6, rest = bx & 63;
        int tmt = rest >> 3, b = rest & 7;
        float* Pd = (y < 2 ? Pa + (long)y * 16 * 65536 : Pb + (long)(y - 2) * 16 * 65536)
                    + (long)b * 65536;                    // hop=0
        hop_tile(F0 + (long)b * SSq, hopVT + (long)b * 65536, y, tmt, Pd, Fs, Hs);
    } else {
        int lane = threadIdx.x & 63, w = threadIdx.x >> 6;
        float w0 = fw[3], w1 = fw[4], w2 = fw[5], b0 = fbv[1];
        long row = (long)(bx - 256) * 4 + w;
        fused_row(A2 + row * 1024, AAt2 + row * 1024, AtA2 + row * 1024,
                  w0, w1, w2, b0, F1 + row * 1024, lane);
    }
}

// hop-1 GEMM standalone, split-K=4: grid 256.
__global__ __launch_bounds__(256) void gemm_hop1(
    const u16* __restrict__ F1, const u16* __restrict__ hopVT,
    float* __restrict__ Pa, float* __restrict__ Pb)
{
    __shared__ u16 Fs[128 * 64];
    __shared__ u16 Hs[64 * 64];
    const long SSq = (long)SS * SS;
    int j = blockIdx.x;
    int y = j >> 6, rest = j & 63;
    int tmt = rest >> 3, b = rest & 7;
    float* Pd = (y < 2 ? Pa + (long)y * 16 * 65536 : Pb + (long)(y - 2) * 16 * 65536)
                + (long)(8 + b) * 65536;                  // hop=1
    hop_tile(F1 + (long)b * SSq, hopVT + (long)(8 + b) * 65536, y, tmt, Pd, Fs, Hs);
}

// ---------------------------------------------------------------------------
// Generic batched NT GEMM (final projection): C[z] = X[z](MxK) * Y[z]^T(NxK)
// ---------------------------------------------------------------------------
__global__ __launch_bounds__(256) void gemm_nt(
    const u16* __restrict__ X, long sx,
    const u16* __restrict__ Y, long sy,
    void* __restrict__ Cv, long sc,
    int M, int N, int K, int cf32)
{
    __shared__ u16 Xs[128 * 64];
    __shared__ u16 Ys[128 * 64];
    const u16* Xb = X + (long)blockIdx.z * sx;
    const u16* Yb = Y + (long)blockIdx.z * sy;
    int tm = blockIdx.x * 128, tn = blockIdx.y * 128;
    int t = threadIdx.x, lane = t & 63, w = t >> 6;
    int wm = (w & 1) << 6, wn = (w >> 1) << 6;
    int fr = lane & 15, q = lane >> 4, m7 = fr & 7;
    int subrow = lane >> 3, cch = (lane & 7) ^ subrow;

    const u16* xg[4]; const u16* yg[4]; u16* xl[4]; u16* yl[4];
    #pragma unroll
    for (int i = 0; i < 4; i++) {
        int r = i * 32 + w * 8 + subrow;
        xg[i] = Xb + (long)(tm + r) * K + cch * 8;
        yg[i] = Yb + (long)(tn + r) * K + cch * 8;
        xl[i] = Xs + (i * 32 + w * 8) * 64;
        yl[i] = Ys + (i * 32 + w * 8) * 64;
    }

    v4f acc[4][4];
    #pragma unroll
    for (int i = 0; i < 4; i++)
        #pragma unroll
        for (int j = 0; j < 4; j++) {
            acc[i][j][0] = 0.f; acc[i][j][1] = 0.f; acc[i][j][2] = 0.f; acc[i][j][3] = 0.f;
        }

    for (int k0 = 0; k0 < K; k0 += 64) {
        __syncthreads();
        #pragma unroll
        for (int i = 0; i < 4; i++) { gload16(xg[i] + k0, xl[i]); gload16(yg[i] + k0, yl[i]); }
        __syncthreads();
        v8s af[2][4], bfr[2][4];
        #pragma unroll
        for (int h = 0; h < 2; h++) {
            int ca = (((h << 2) + q) ^ m7) << 3;
            #pragma unroll
            for (int s = 0; s < 4; s++) {
                af[h][s]  = *(const v8s*)(Xs + (wm + s * 16 + fr) * 64 + ca);
                bfr[h][s] = *(const v8s*)(Ys + (wn + s * 16 + fr) * 64 + ca);
            }
        }
        #pragma unroll
        for (int h = 0; h < 2; h++)
            #pragma unroll
            for (int i = 0; i < 4; i++)
                #pragma unroll
                for (int j = 0; j < 4; j++)
                    acc[i][j] = __builtin_amdgcn_mfma_f32_16x16x32_bf16(af[h][i], bfr[h][j], acc[i][j], 0, 0, 0);
    }
    long cb = (long)blockIdx.z * sc;
    #pragma unroll
    for (int i = 0; i < 4; i++) {
        int rowb = tm + wm + i * 16 + q * 4;
        #pragma unroll
        for (int j = 0; j < 4; j++) {
            int col = tn + wn + j * 16 + fr;
            #pragma unroll
            for (int r = 0; r < 4; r++) {
                long o = cb + (long)(rowb + r) * N + col;
                if (cf32) ((float*)Cv)[o] = acc[i][j][r];
                else      ((u16*)Cv)[o] = f2bf(acc[i][j][r]);
            }
        }
    }
}

// ---------------------------------------------------------------------------
// Projection GEMM with FUSED x fp32->bf16 conversion (reg-staged, RNE f2bf —
// numerics identical to the old pack; the mapping was verified in R4) and
// FUSED RoPE + gate-softmax epilogue. 128 blocks x 256 thr (R3 geometry).
// Next-iter x loads are issued INSIDE the MFMA segment so their ~HBM latency
// hides under the 32 MFMAs; single xr buffer is hazard-free (written after
// its reader, separated by a barrier). Block-id swizzle puts each tm-tile's
// two (by) readers on the same XCD so the 2nd 256KB x-read is an L2 hit.
// ---------------------------------------------------------------------------
__global__ __launch_bounds__(256) void k_proj_rope(
    const float* __restrict__ x, const u16* __restrict__ wpack,
    const float* __restrict__ gateb, const float2* __restrict__ ropetab,
    u16* __restrict__ Qb, u16* __restrict__ Kb, u16* __restrict__ Vb,
    float* __restrict__ gate)
{
    __shared__ u16 Xs[128 * 64];
    __shared__ u16 Ys[128 * 64];
    // bid -> (tmt, by): groups of 16 blocks share XCD residues; by split inside.
    int bid = blockIdx.x;
    int ggrp = bid >> 4, rem = bid & 15, by = rem >> 3, xi = rem & 7;
    int tmt = ggrp * 8 + xi;                 // 0..63
    int tm = tmt * 128, tn = by * 128;
    int t = threadIdx.x, lane = t & 63, w = t >> 6;
    int wm = (w & 1) << 6, wn = (w >> 1) << 6;
    int fr = lane & 15, q = lane >> 4, m7 = fr & 7;
    int subrow = lane >> 3, cch = (lane & 7) ^ subrow;

    const u16* yg[4]; u16* yl[4];
    const float* xg[4]; u16* xw[4];
    #pragma unroll
    for (int i = 0; i < 4; i++) {
        int r = i * 32 + w * 8 + subrow;
        yg[i] = wpack + (long)(tn + r) * 512 + cch * 8;
        yl[i] = Ys + (i * 32 + w * 8) * 64;
        xg[i] = x + (long)(tm + r) * 512 + cch * 8;
        xw[i] = Xs + (i * 32 + w * 8) * 64 + lane * 8;   // == gload16's lane slot
    }

    v4f acc[4][4];
    #pragma unroll
    for (int i = 0; i < 4; i++)
        #pragma unroll
        for (int j = 0; j < 4; j++) {
            acc[i][j][0] = 0.f; acc[i][j][1] = 0.f; acc[i][j][2] = 0.f; acc[i][j][3] = 0.f;
        }

    // prefetch iter-0 x into registers
    float4 xr[4][2];
    #pragma unroll
    for (int i = 0; i < 4; i++) {
        xr[i][0] = *(const float4*)(xg[i]);
        xr[i][1] = *(const float4*)(xg[i] + 4);
    }

    for (int k0 = 0; k0 < 512; k0 += 64) {
        __syncthreads();                       // prev tile fully consumed
        #pragma unroll
        for (int i = 0; i < 4; i++) gload16(yg[i] + k0, yl[i]);
        #pragma unroll
        for (int i = 0; i < 4; i++) {
            v8s pk;
            pk[0] = (short)f2bf(xr[i][0].x); pk[1] = (short)f2bf(xr[i][0].y);
            pk[2] = (short)f2bf(xr[i][0].z); pk[3] = (short)f2bf(xr[i][0].w);
            pk[4] = (short)f2bf(xr[i][1].x); pk[5] = (short)f2bf(xr[i][1].y);
            pk[6] = (short)f2bf(xr[i][1].z); pk[7] = (short)f2bf(xr[i][1].w);
            *(v8s*)xw[i] = pk;
        }
        __syncthreads();                       // drains W gloads + x ds_writes
        v8s af[2][4], bfr[2][4];
        #pragma unroll
        for (int h = 0; h < 2; h++) {
            int ca = (((h << 2) + q) ^ m7) << 3;
            #pragma unroll
            for (int s = 0; s < 4; s++) {
                af[h][s]  = *(const v8s*)(Xs + (wm + s * 16 + fr) * 64 + ca);
                bfr[h][s] = *(const v8s*)(Ys + (wn + s * 16 + fr) * 64 + ca);
            }
        }
        if (k0 + 64 < 512) {                   // issue next x loads; hide under MFMA
            #pragma unroll
            for (int i = 0; i < 4; i++) {
                xr[i][0] = *(const float4*)(xg[i] + k0 + 64);
                xr[i][1] = *(const float4*)(xg[i] + k0 + 68);
            }
        }
        #pragma unroll
        for (int h = 0; h < 2; h++)
            #pragma unroll
            for (int i = 0; i < 4; i++)
                #pragma unroll
                for (int j = 0; j < 4; j++)
                    acc[i][j] = __builtin_amdgcn_mfma_f32_16x16x32_bf16(af[h][i], bfr[h][j], acc[i][j], 0, 0, 0);
    }

    if (by == 0) {
        // Q (wn=0) or K (wn=64): rope. col l = j*16+fr; partner l^32 = acc[i][j^2][r].
        u16* dst = wn ? Kb : Qb;
        #pragma unroll
        for (int i = 0; i < 4; i++) {
            #pragma unroll
            for (int r = 0; r < 4; r++) {
                int row = tm + wm + i * 16 + q * 4 + r;
                int spos = row & (SS - 1);
                float2 t0 = ropetab[spos * 32 + fr];        // f = fr   (j even)
                float2 t1 = ropetab[spos * 32 + 16 + fr];   // f = fr+16 (j odd)
                #pragma unroll
                for (int j = 0; j < 4; j++) {
                    float v = acc[i][j][r], p = acc[i][j ^ 2][r];
                    float cs = (j & 1) ? t1.x : t0.x;
                    float sn = (j & 1) ? t1.y : t0.y;
                    float o = (j & 2) ? (v * cs + p * sn) : (v * cs - p * sn);
                    dst[(long)row * 64 + j * 16 + fr] = f2bf(o);
                }
            }
        }
    } else if (wn == 0) {
        // V: cols 128..191 -> l = j*16+fr
        #pragma unroll
        for (int i = 0; i < 4; i++)
            #pragma unroll
            for (int j = 0; j < 4; j++)
                #pragma unroll
                for (int r = 0; r < 4; r++) {
                    int row = tm + wm + i * 16 + q * 4 + r;
                    Vb[(long)row * 64 + j * 16 + fr] = f2bf(acc[i][j][r]);
                }
    } else {
        // gate: cols 192/193 = j=0, fr in {0,1}. softmax over the pair.
        float gb = gateb[fr & 1];
        #pragma unroll
        for (int i = 0; i < 4; i++)
            #pragma unroll
            for (int r = 0; r < 4; r++) {
                int row = tm + wm + i * 16 + q * 4 + r;
                float g = acc[i][0][r] + gb;
                float go = __shfl_xor(g, 1);
                float m = fmaxf(g, go);
                float e = __expf(g - m), eo = __expf(go - m);
                if (fr < 2) gate[(long)row * 2 + fr] = e / (e + eo);
            }
    }
}

// pack weights to bf16 + rope cos/sin table (x-pack removed: proj reads x).
__global__ __launch_bounds__(256) void k_pack(
    const float* __restrict__ Wq, const float* __restrict__ Wk,
    const float* __restrict__ Wv, const float* __restrict__ gW,
    const float* __restrict__ hopW, const float* __restrict__ outW,
    u16* __restrict__ wpack, u16* __restrict__ hopWb, u16* __restrict__ outWb,
    float2* __restrict__ ropetab)
{
    int bx = blockIdx.x;
    if (bx < 672) {
        int idx = bx * 256 + threadIdx.x;
        if (idx < 131072) {
            int r = idx >> 9, c = idx & 511;
            float v = 0.f;
            if (r < 64)       v = Wq[r * 512 + c];
            else if (r < 128) v = Wk[(r - 64) * 512 + c];
            else if (r < 192) v = Wv[(r - 128) * 512 + c];
            else if (r < 194) v = gW[(r - 192) * 512 + c];
            wpack[idx] = f2bf(v);
        } else if (idx < 131072 + 8192) {
            int i = idx - 131072;
            hopWb[i] = f2bf(hopW[i]);
        } else if (idx < 131072 + 8192 + 32768) {
            int i = idx - 131072 - 8192;
            outWb[i] = f2bf(outW[i]);
        }
    } else {
        int idx = (bx - 672) * 256 + threadIdx.x;   // 0..32767
        int spos = idx >> 5, f = idx & 31;
        float ang = (float)spos * exp2f(-(float)f * (13.287712379549449f / 32.0f));
        float sn, cs;
        sincosf(ang, &sn, &cs);
        ropetab[idx] = make_float2(cs, sn);
    }
}

// sum split-K=4 partials, gate-combine -> comb bf16 [8192][64].
// Vectorized: 4 elems/thread (same row), 8x float4 reads + ushort4 store.
__global__ __launch_bounds__(256) void k_combine(
    const float* __restrict__ Pa, const float* __restrict__ Pb,
    const float* __restrict__ gate, u16* __restrict__ comb)
{
    long idx = ((long)blockIdx.x * 256 + threadIdx.x) * 4;   // 8192*64 total
    long srow = idx >> 6;
    int b = (int)(srow >> 10);
    long o = (long)(srow & 1023) * 64 + (idx & 63);
    float4 a0 = *(const float4*)(Pa + (long)b * 65536 + o);
    float4 a1 = *(const float4*)(Pa + (long)(16 + b) * 65536 + o);
    float4 b0 = *(const float4*)(Pb + (long)b * 65536 + o);
    float4 b1 = *(const float4*)(Pb + (long)(16 + b) * 65536 + o);
    float4 c0 = *(const float4*)(Pa + (long)(8 + b) * 65536 + o);
    float4 c1 = *(const float4*)(Pa + (long)(24 + b) * 65536 + o);
    float4 d0 = *(const float4*)(Pb + (long)(8 + b) * 65536 + o);
    float4 d1 = *(const float4*)(Pb + (long)(24 + b) * 65536 + o);
    float g0 = gate[srow * 2], g1 = gate[srow * 2 + 1];
    ushort4 ov;
    ov.x = f2bf((a0.x + a1.x + b0.x + b1.x) * g0 + (c0.x + c1.x + d0.x + d1.x) * g1);
    ov.y = f2bf((a0.y + a1.y + b0.y + b1.y) * g0 + (c0.y + c1.y + d0.y + d1.y) * g1);
    ov.z = f2bf((a0.z + a1.z + b0.z + b1.z) * g0 + (c0.z + c1.z + d0.z + d1.z) * g1);
    ov.w = f2bf((a0.w + a1.w + b0.w + b1.w) * g0 + (c0.w + c1.w + d0.w + d1.w) * g1);
    *(ushort4*)(comb + idx) = ov;
}

// ---------------------------------------------------------------------------
extern "C" void kernel_launch(void* const* d_in, const int* in_sizes, int n_in,
                              void* d_out, int out_size, void* d_ws, size_t ws_size,
                              hipStream_t stream) {
    const float* x    = (const float*)d_in[0];
    const float* Wq   = (const float*)d_in[1];
    const float* Wk   = (const float*)d_in[2];
    const float* Wv   = (const float*)d_in[3];
    const float* btab = (const float*)d_in[4];
    const float* fw   = (const float*)d_in[5];
    const float* fbv  = (const float*)d_in[6];
    const float* hopW = (const float*)d_in[7];
    const float* gW   = (const float*)d_in[8];
    const float* gb   = (const float*)d_in[9];
    const float* outW = (const float*)d_in[10];
    const float* temp = (const float*)d_in[11];
    float* out = (float*)d_out;

    char* wsb = (char*)d_ws;
    size_t off = 0;
    auto take = [&](size_t n) { char* p = wsb + off; off += (n + 255) & ~(size_t)255; return p; };
    u16* Qb      = (u16*)take(8192L * 64 * 2);
    u16* Kb      = (u16*)take(8192L * 64 * 2);
    u16* Vb      = (u16*)take(8192L * 64 * 2);
    float* gate  = (float*)take(8192L * 2 * 4);
    u16* wpack   = (u16*)take(256L * 512 * 2);
    u16* hopWb   = (u16*)take(2L * 64 * 64 * 2);
    u16* outWb   = (u16*)take(512L * 64 * 2);
    float2* ropetab = (float2*)take(1024L * 32 * 8);
    u16* hopVT   = (u16*)take(2L * 8 * 64 * 1024 * 2);
    float* Pa    = (float*)take(2L * 16 * 65536 * 4);     // split-K partials y=0,1
    u16* comb    = (u16*)take(8192L * 64 * 2);
    char* fregion = take(8L * 1024 * 1024 * 4);       // 32 MB region for F0/F1
    u16* F0      = (u16*)fregion;
    u16* F1      = (u16*)fregion + 8L * 1024 * 1024;  // second 16 MB of region
    u16* A       = (u16*)take(8L * 1024 * 1024 * 2);
    u16* AT      = (u16*)take(8L * 1024 * 1024 * 2);
    float* Pb    = (float*)AT;                        // alias: AT dead after link1
    u16* AAt     = (u16*)take(8L * 1024 * 1024 * 2);
    u16* AtA     = (u16*)take(8L * 1024 * 1024 * 2);
    u16* A2      = (u16*)take(8L * 1024 * 1024 * 2);
    u16* AAt2    = (u16*)take(8L * 1024 * 1024 * 2);
    u16* AtA2    = (u16*)take(8L * 1024 * 1024 * 2);
    (void)ws_size; (void)in_sizes; (void)n_in; (void)out_size;

    // 1. pack weights + rope table (x-pack eliminated; proj converts x inline)
    k_pack<<<800, 256, 0, stream>>>(Wq, Wk, Wv, gW, hopW, outW, wpack,
                                    hopWb, outWb, ropetab);
    // 2. projection GEMM reading x directly (reg-staged cvt, MFMA-hidden
    //    prefetch) + fused rope + gate softmax
    k_proj_rope<<<128, 256, 0, stream>>>(x, wpack, gb, ropetab,
                                         Qb, Kb, Vb, gate);
    // 3. fused QK^T + bias + softmax -> A, AT (no fp32 scores round-trip)
    k_qksm<<<512, 256, 0, stream>>>(Qb, Kb, btab, temp, A, AT);
    // 4. generation-1: AAt, AtA (reg-mirrored) + A2 + hopV rider -> hopVT
    gemm_link1<<<1152, 256, 0, stream>>>(A, AT, AAt, AtA, A2, Vb, hopWb, hopVT);
    // 5. gen-2 sym pair (576 GEMM blocks first) + fused hop-0 rows (2048)
    k_link2_fused0<<<2624, 256, 0, stream>>>(AAt, AtA, AAt2, AtA2, A, fw, fbv, F0);
    // 6. hop-0 GEMM tail (256 first) + fused hop-1 rows (2048)
    k_hop0_fused1<<<2304, 256, 0, stream>>>(F0, hopVT, Pa, Pb, A2, AAt2, AtA2,
                                            fw, fbv, F1);
    // 7. hop-1 GEMM
    gemm_hop1<<<256, 256, 0, stream>>>(F1, hopVT, Pa, Pb);
    // 8. combine (vectorized x4) + output projection
    k_combine<<<512, 256, 0, stream>>>(Pa, Pb, gate, comb);
    gemm_nt<<<dim3(64, 4, 1), 256, 0, stream>>>(comb, 0, outWb, 0, out, 0, 8192, 512, 64, 1);
}